// Round 10
// baseline (474.574 us; speedup 1.0000x reference)
//
#include <hip/hip_runtime.h>
#include <math.h>

typedef unsigned short u16;
typedef __attribute__((ext_vector_type(8))) short bf16x8;
typedef __attribute__((ext_vector_type(4))) float f32x4;

#define NN 32768      // total nodes
#define EDGES 524288  // total edges
#define NB 64         // graphs
#define NPG 512       // nodes per graph
#define EPG 8192      // edges per graph (contiguous in src/dst)
#define KEEP 256      // kept per graph
#define D 512         // feature dim

__device__ __forceinline__ float b2f(u16 h){ return __uint_as_float(((unsigned)h)<<16); }
__device__ __forceinline__ u16 f2b(float f){
  unsigned u = __float_as_uint(f);
  unsigned r = u + 0x7FFFu + ((u>>16)&1u);   // RNE
  return (u16)(r>>16);
}

// async global->LDS, 16B per lane (dest must be wave-uniform base + lane*16)
__device__ __forceinline__ void gload16(const void* g, void* l){
  __builtin_amdgcn_global_load_lds((const __attribute__((address_space(1))) void*)g,
                                   (__attribute__((address_space(3))) void*)l, 16, 0, 0);
}

// ---------- dtype detection: are float inputs f32 (flag=1) or bf16 (flag=0)? ----------
__global__ __launch_bounds__(256) void detect_kernel(const u16* __restrict__ xb, int* __restrict__ flags){
  __shared__ int cnt;
  if (threadIdx.x==0) cnt = 0;
  __syncthreads();
  u16 v = xb[threadIdx.x];
  int e = (v>>7)&0xFF;
  if (e > 140) atomicAdd(&cnt, 1);
  __syncthreads();
  if (threadIdx.x==0){ flags[0] = (cnt > 8) ? 1 : 0; flags[1] = 1; }
}

// ---------- fused per-graph preprocessing: degrees, norms, rowp, CSR fill ----------
// One block per graph (512 threads). Graph g owns edges [g*EPG, (g+1)*EPG); all
// endpoints lie in [g*NPG, (g+1)*NPG) so local id = v & 511. rowp is bit-identical
// to a global scan since each graph has exactly EPG in-edges.
__global__ __launch_bounds__(512) void graphprep_kernel(
    const int* __restrict__ src, const int* __restrict__ dst,
    float* __restrict__ no, float* __restrict__ ni,
    int* __restrict__ rowp, int* __restrict__ csr)
{
  __shared__ int dego[NPG], degi[NPG], s[NPG], start[NPG], cur[NPG];
  int g = blockIdx.x, n = threadIdx.x;
  dego[n] = 0; degi[n] = 0; cur[n] = 0;
  __syncthreads();
  int ebase = g*EPG;
  #pragma unroll
  for (int i = 0; i < 16; i++){
    int e = ebase + n + i*512;
    atomicAdd(&dego[src[e] & (NPG-1)], 1);
    atomicAdd(&degi[dst[e] & (NPG-1)], 1);
  }
  __syncthreads();
  int di = degi[n];
  s[n] = di;
  __syncthreads();
  for (int off=1; off<NPG; off<<=1){
    int val = (n>=off) ? s[n-off] : 0;
    __syncthreads();
    s[n] += val;
    __syncthreads();
  }
  int excl = s[n] - di;
  start[n] = excl;
  int a = dego[n]; if (a<1) a=1;
  int b = di;      if (b<1) b=1;
  int v = g*NPG + n;
  no[v] = (float)(1.0/sqrt((double)a));
  ni[v] = (float)(1.0/sqrt((double)b));
  rowp[v] = ebase + excl;
  if (g == NB-1 && n == NPG-1) rowp[NN] = EDGES;
  __syncthreads();
  #pragma unroll
  for (int i = 0; i < 16; i++){
    int e = ebase + n + i*512;
    int dl = dst[e] & (NPG-1);
    int pos = atomicAdd(&cur[dl], 1);
    csr[ebase + start[dl] + pos] = src[e];
  }
}

// ---------- small-tensor conversion to canonical f32 ----------
__global__ __launch_bounds__(512) void bcvt_kernel(const int* __restrict__ flags,
    const void* b1, const void* b2, const void* sW1, const void* sW2,
    const void* sb1, const void* sb2,
    float* b1c, float* b2c, float* sW1c, float* sW2c, float* sbc)
{
  int t = threadIdx.x;
  int f = flags[0];
  #define CV(p,i) (f ? ((const float*)(p))[i] : b2f(((const u16*)(p))[i]))
  b1c[t]  = CV(b1, t);
  b2c[t]  = CV(b2, t);
  sW1c[t] = CV(sW1, t);
  sW2c[t] = CV(sW2, t);
  if (t==0){ sbc[0] = CV(sb1,0); sbc[1] = CV(sb2,0); }
  #undef CV
}

// ---------- weight transpose + hi/lo bf16 split ----------
__global__ void tsplit_kernel(const int* __restrict__ flags, const void* __restrict__ W,
                              u16* __restrict__ WTh, u16* __restrict__ WTl){
  __shared__ float tile[32][33];
  int f = flags[0];
  int bx = blockIdx.x*32, by = blockIdx.y*32;
  int tx = threadIdx.x, ty = threadIdx.y; // (32,8)
  #pragma unroll
  for (int i=0;i<4;i++){
    size_t idx = (size_t)(by+ty+i*8)*D + bx+tx;
    tile[ty+i*8][tx] = f ? ((const float*)W)[idx] : b2f(((const u16*)W)[idx]);
  }
  __syncthreads();
  #pragma unroll
  for (int i=0;i<4;i++){
    float v = tile[tx][ty+i*8];
    u16 h = f2b(v);
    size_t o = (size_t)(bx+ty+i*8)*D + by+tx;
    WTh[o] = h;
    WTl[o] = f2b(v - b2f(h));
  }
}

// ---------- x split: f32 (or bf16) -> bf16 hi/lo ----------
__global__ __launch_bounds__(256) void xsplit_kernel(const void* __restrict__ X,
    const int* __restrict__ flags, u16* __restrict__ Xh, u16* __restrict__ Xl)
{
  size_t i = ((size_t)blockIdx.x*256 + threadIdx.x)*4;
  float v0,v1,v2,v3;
  if (flags[0]){
    float4 f = *(const float4*)((const float*)X + i);
    v0=f.x; v1=f.y; v2=f.z; v3=f.w;
  } else {
    ushort4 uv = *(const ushort4*)((const u16*)X + i);
    v0=b2f(uv.x); v1=b2f(uv.y); v2=b2f(uv.z); v3=b2f(uv.w);
  }
  ushort4 hh, hl;
  hh.x=f2b(v0); hl.x=f2b(v0-b2f(hh.x));
  hh.y=f2b(v1); hl.y=f2b(v1-b2f(hh.y));
  hh.z=f2b(v2); hl.z=f2b(v2-b2f(hh.z));
  hh.w=f2b(v3); hl.w=f2b(v3-b2f(hh.w));
  *(ushort4*)(Xh+i) = hh;
  *(ushort4*)(Xl+i) = hl;
}

// ---------------- GEMM: C = (A @ W) * rowscale; A,B pre-split bf16 hi/lo ----------------
// 256x128 tile, 4 waves (2M x 2N, each wave 128x64 output), BK=32, SINGLE-buffered
// 48 KB LDS -> 2-3 blocks/CU: barrier drain hidden by other blocks' MFMA (m97/m114
// TLP pattern). 96 MFMA / K-step / wave. Grid 512, XCD-pinned.

__device__ __forceinline__ void gemm_tile_bm(int id, int& brow, int& bcol){
  int xcd = id & 7, k = id >> 3;           // k: 0..63
  brow = (xcd + 8*(k >> 2)) * 256;         // all 4 bcol-blocks of a panel -> same XCD
  bcol = (k & 3) * 128;
}

__global__ __launch_bounds__(256) void gemm_bm(
    const u16* __restrict__ Ahg, const u16* __restrict__ Alg,
    const u16* __restrict__ BTh, const u16* __restrict__ BTl,
    float* __restrict__ C, const float* __restrict__ rowscale)
{
  // A chunks: c = q*256 + row (q 0..3, 16 B each) ; B chunks: c = q*128 + row
  __shared__ alignas(16) u16 AhL[1024*8], AlL[1024*8], BhL[512*8], BlL[512*8];
  int t = threadIdx.x;
  int brow, bcol;
  gemm_tile_bm(blockIdx.x, brow, bcol);
  int wid = t>>6, lane = t&63;
  int wr = wid>>1, wc = wid&1;             // wave grid 2 x 2, wave owns 128x64
  int q = lane>>4, r = lane&15;
  f32x4 acc[8][4] = {};

  // staging: thread t owns A row brow+t (4 q-chunks) and B row bcol+(t&127), q = (t>>7)+{0,2}
  const u16* pAh = Ahg + (size_t)(brow + t)*D;
  const u16* pAl = Alg + (size_t)(brow + t)*D;
  int Brow = t & 127, Bq = t >> 7;
  const u16* pBh = BTh + (size_t)(bcol + Brow)*D + Bq*8;
  const u16* pBl = BTl + (size_t)(bcol + Brow)*D + Bq*8;

  for (int kt=0; kt<16; kt++){
    int ko = kt*32;
    __syncthreads();                       // previous K-step's frags consumed
    #pragma unroll
    for (int i=0;i<4;i++){
      gload16(pAh+ko+i*8, AhL + (i*256+t)*8);
      gload16(pAl+ko+i*8, AlL + (i*256+t)*8);
    }
    #pragma unroll
    for (int i=0;i<2;i++){
      gload16(pBh+ko+i*16, BhL + ((Bq+2*i)*128 + Brow)*8);
      gload16(pBl+ko+i*16, BlL + ((Bq+2*i)*128 + Brow)*8);
    }
    __syncthreads();                       // compiler emits vmcnt(0) drain: tile ready
    bf16x8 fbh[4], fbl[4];
    #pragma unroll
    for (int n=0;n<4;n++){
      fbh[n] = *(const bf16x8*)(&BhL[(q*128 + wc*64 + n*16 + r)*8]);
      fbl[n] = *(const bf16x8*)(&BlL[(q*128 + wc*64 + n*16 + r)*8]);
    }
    __builtin_amdgcn_s_setprio(1);
    #pragma unroll
    for (int m=0;m<8;m++){
      bf16x8 fah = *(const bf16x8*)(&AhL[(q*256 + wr*128 + m*16 + r)*8]);
      bf16x8 fal = *(const bf16x8*)(&AlL[(q*256 + wr*128 + m*16 + r)*8]);
      #pragma unroll
      for (int n=0;n<4;n++){
        acc[m][n] = __builtin_amdgcn_mfma_f32_16x16x32_bf16(fah, fbh[n], acc[m][n], 0,0,0);
        acc[m][n] = __builtin_amdgcn_mfma_f32_16x16x32_bf16(fah, fbl[n], acc[m][n], 0,0,0);
        acc[m][n] = __builtin_amdgcn_mfma_f32_16x16x32_bf16(fal, fbh[n], acc[m][n], 0,0,0);
      }
    }
    __builtin_amdgcn_s_setprio(0);
  }

  #pragma unroll
  for (int m=0;m<8;m++){
    int rowb = brow + wr*128 + m*16 + q*4;
    #pragma unroll
    for (int n=0;n<4;n++){
      int col = bcol + wc*64 + n*16 + r;
      #pragma unroll
      for (int g=0; g<4; g++){
        int row = rowb + g;
        C[(size_t)row*D + col] = acc[m][n][g] * rowscale[row];
      }
    }
  }
}

// -------- edge aggregation: relu( (sum_{u in N(v)} Y[u]) * ni[v] + b ) --------
// 2 nodes/block, 128 threads/node. CSR row hoisted into lane registers, indices via
// shfl; gather unrolled x8 (8 independent L2 accesses in flight). XCD-pinned per graph.
// mode 0: write split bf16 hi/lo.  mode 1: write f32 H + fused score dots.

__global__ __launch_bounds__(256) void agg_kernel(
    const float* __restrict__ Y, const int* __restrict__ rowp,
    const int* __restrict__ csr, const float* __restrict__ ni,
    const float* __restrict__ bias, float* __restrict__ H,
    u16* __restrict__ Hh, u16* __restrict__ Hl,
    const float* __restrict__ sW1, const float* __restrict__ sW2,
    float* __restrict__ t1, float* __restrict__ t2, int mode)
{
  int i = blockIdx.x;
  int xcd = i & 7, j = i >> 3;              // j: 0..2047
  int half = threadIdx.x >> 7;              // node within pair
  int t = threadIdx.x & 127;                // float4 chunk
  int lane = threadIdx.x & 63;
  int v = (xcd + 8*(j >> 8))*NPG + ((j & 255)*2 + half);
  int rp0 = rowp[v], rp1 = rowp[v+1];
  const float4* Yv = (const float4*)Y;
  float4 a = {0.f,0.f,0.f,0.f};
  for (int eb = rp0; eb < rp1; eb += 64){
    int cnt = rp1 - eb; if (cnt > 64) cnt = 64;
    int idx = (lane < cnt) ? csr[eb + lane] : 0;
    int e = 0;
    for (; e+8 <= cnt; e += 8){
      int u0 = __shfl(idx, e),   u1 = __shfl(idx, e+1);
      int u2 = __shfl(idx, e+2), u3 = __shfl(idx, e+3);
      int u4 = __shfl(idx, e+4), u5 = __shfl(idx, e+5);
      int u6 = __shfl(idx, e+6), u7 = __shfl(idx, e+7);
      float4 y0 = Yv[(size_t)u0*128 + t];
      float4 y1 = Yv[(size_t)u1*128 + t];
      float4 y2 = Yv[(size_t)u2*128 + t];
      float4 y3 = Yv[(size_t)u3*128 + t];
      float4 y4 = Yv[(size_t)u4*128 + t];
      float4 y5 = Yv[(size_t)u5*128 + t];
      float4 y6 = Yv[(size_t)u6*128 + t];
      float4 y7 = Yv[(size_t)u7*128 + t];
      a.x += ((y0.x + y1.x) + (y2.x + y3.x)) + ((y4.x + y5.x) + (y6.x + y7.x));
      a.y += ((y0.y + y1.y) + (y2.y + y3.y)) + ((y4.y + y5.y) + (y6.y + y7.y));
      a.z += ((y0.z + y1.z) + (y2.z + y3.z)) + ((y4.z + y5.z) + (y6.z + y7.z));
      a.w += ((y0.w + y1.w) + (y2.w + y3.w)) + ((y4.w + y5.w) + (y6.w + y7.w));
    }
    for (; e+4 <= cnt; e += 4){
      int u0 = __shfl(idx, e),   u1 = __shfl(idx, e+1);
      int u2 = __shfl(idx, e+2), u3 = __shfl(idx, e+3);
      float4 y0 = Yv[(size_t)u0*128 + t];
      float4 y1 = Yv[(size_t)u1*128 + t];
      float4 y2 = Yv[(size_t)u2*128 + t];
      float4 y3 = Yv[(size_t)u3*128 + t];
      a.x += (y0.x + y1.x) + (y2.x + y3.x);
      a.y += (y0.y + y1.y) + (y2.y + y3.y);
      a.z += (y0.z + y1.z) + (y2.z + y3.z);
      a.w += (y0.w + y1.w) + (y2.w + y3.w);
    }
    for (; e < cnt; e++){
      int u = __shfl(idx, e);
      float4 y = Yv[(size_t)u*128 + t];
      a.x += y.x; a.y += y.y; a.z += y.z; a.w += y.w;
    }
  }
  float w = ni[v];
  float4 b4 = ((const float4*)bias)[t];
  float4 rr;
  rr.x = fmaxf(a.x*w + b4.x, 0.f);
  rr.y = fmaxf(a.y*w + b4.y, 0.f);
  rr.z = fmaxf(a.z*w + b4.z, 0.f);
  rr.w = fmaxf(a.w*w + b4.w, 0.f);

  if (mode == 0){
    ushort4 hh, hl;
    hh.x = f2b(rr.x); hl.x = f2b(rr.x - b2f(hh.x));
    hh.y = f2b(rr.y); hl.y = f2b(rr.y - b2f(hh.y));
    hh.z = f2b(rr.z); hl.z = f2b(rr.z - b2f(hh.z));
    hh.w = f2b(rr.w); hl.w = f2b(rr.w - b2f(hh.w));
    *(ushort4*)(Hh + (size_t)v*D + t*4) = hh;
    *(ushort4*)(Hl + (size_t)v*D + t*4) = hl;
  } else {
    ((float4*)H)[(size_t)v*128 + t] = rr;
    float4 w1 = ((const float4*)sW1)[t];
    float4 w2 = ((const float4*)sW2)[t];
    float p1 = rr.x*w1.x + rr.y*w1.y + rr.z*w1.z + rr.w*w1.w;
    float p2 = rr.x*w2.x + rr.y*w2.y + rr.z*w2.z + rr.w*w2.w;
    #pragma unroll
    for (int off=32; off>=1; off>>=1){
      p1 += __shfl_xor(p1, off);
      p2 += __shfl_xor(p2, off);
    }
    __shared__ float red1[4], red2[4];
    int wv = threadIdx.x>>6;
    if (lane==0){ red1[wv] = p1; red2[wv] = p2; }
    __syncthreads();
    if (t==0){
      t1[v] = red1[half*2] + red1[half*2+1];
      t2[v] = red2[half*2] + red2[half*2+1];
    }
  }
}

// -------- fused score aggregation + per-graph stable top-K --------

__global__ __launch_bounds__(512) void scoretopk_kernel(
    const float* __restrict__ t1, const float* __restrict__ t2,
    const int* __restrict__ rowp, const int* __restrict__ csr,
    const float* __restrict__ no, const float* __restrict__ ni,
    const float* __restrict__ sbc,
    int* __restrict__ perm, float* __restrict__ gate)
{
  __shared__ unsigned long long key[NPG];
  __shared__ float scl[NPG];
  int g = blockIdx.x, n = threadIdx.x;
  int v = g*NPG + n;
  double a1 = 0.0, a2 = 0.0;
  int rp1 = rowp[v+1];
  for (int e=rowp[v]; e<rp1; e++){
    int u = csr[e];
    double w = (double)no[u];
    a1 += (double)t1[u]*w;
    a2 += (double)t2[u]*w;
  }
  double wi = (double)ni[v];
  double s1 = a1*wi + (double)sbc[0];
  double s2 = a2*wi + (double)sbc[1];
  float s = (float)(0.5*(s1+s2));
  scl[n] = s;
  unsigned u = __float_as_uint(s);
  u = (u & 0x80000000u) ? ~u : (u | 0x80000000u);  // order-preserving (ascending)
  unsigned kd = ~u;                                 // descending score
  key[n] = ((unsigned long long)kd<<32) | (unsigned)n;
  __syncthreads();
  for (int k=2; k<=NPG; k<<=1){
    for (int j=k>>1; j>0; j>>=1){
      int ixj = n ^ j;
      if (ixj > n){
        unsigned long long a = key[n], b = key[ixj];
        bool up = ((n & k) == 0);
        if ((a > b) == up){ key[n] = b; key[ixj] = a; }
      }
      __syncthreads();
    }
  }
  if (n < KEEP){
    unsigned long long e = key[n];
    int idx = (int)(e & 0xFFFFFFFFull);
    perm[g*KEEP + n] = g*NPG + idx;
    gate[g*KEEP + n] = tanhf(scl[idx]);
  }
}

// -------- fused gated gather + readout (pooled rows + max||sum), f32 outputs --------

__global__ __launch_bounds__(256) void readout_kernel(const float* __restrict__ H,
    const int* __restrict__ perm, const float* __restrict__ gate,
    float* __restrict__ outp, float* __restrict__ outg)
{
  __shared__ int sp[KEEP];
  __shared__ float sg[KEEP];
  __shared__ float4 redmx[128], redsm[128];
  int g = blockIdx.x, t = threadIdx.x;
  int half = t >> 7, c = t & 127;
  sp[t] = perm[g*KEEP + t];
  sg[t] = gate[g*KEEP + t];
  __syncthreads();
  float4 mx = {-INFINITY,-INFINITY,-INFINITY,-INFINITY};
  float4 sm = {0.f,0.f,0.f,0.f};
  for (int rI = half; rI < KEEP; rI += 2){
    int node = sp[rI];
    float gt = sg[rI];
    float4 y = ((const float4*)(H + (size_t)node*D))[c];
    float4 vv;
    vv.x = y.x*gt; vv.y = y.y*gt; vv.z = y.z*gt; vv.w = y.w*gt;
    ((float4*)(outp + (size_t)(g*KEEP + rI)*D))[c] = vv;
    mx.x = fmaxf(mx.x, vv.x); mx.y = fmaxf(mx.y, vv.y);
    mx.z = fmaxf(mx.z, vv.z); mx.w = fmaxf(mx.w, vv.w);
    sm.x += vv.x; sm.y += vv.y; sm.z += vv.z; sm.w += vv.w;
  }
  if (half == 1){ redmx[c] = mx; redsm[c] = sm; }
  __syncthreads();
  if (half == 0){
    float4 omx = redmx[c], osm = redsm[c];
    mx.x = fmaxf(mx.x, omx.x); mx.y = fmaxf(mx.y, omx.y);
    mx.z = fmaxf(mx.z, omx.z); mx.w = fmaxf(mx.w, omx.w);
    sm.x += osm.x; sm.y += osm.y; sm.z += osm.z; sm.w += osm.w;
    ((float4*)(outg + (size_t)g*1024))[c] = mx;
    ((float4*)(outg + (size_t)g*1024 + 512))[c] = sm;
  }
}

// ---------------- launch ----------------

extern "C" void kernel_launch(void* const* d_in, const int* in_sizes, int n_in,
                              void* d_out, int out_size, void* d_ws, size_t ws_size,
                              hipStream_t stream)
{
  (void)in_sizes; (void)n_in; (void)out_size; (void)ws_size;
  const void* x   = d_in[0];
  const int* src  = (const int*)d_in[1];
  const int* dst  = (const int*)d_in[2];
  const void* W1  = d_in[3];
  const void* b1  = d_in[4];
  const void* W2  = d_in[5];
  const void* b2  = d_in[6];
  const void* sW1 = d_in[7];
  const void* sb1 = d_in[8];
  const void* sW2 = d_in[9];
  const void* sb2 = d_in[10];
  float* out = (float*)d_out;

  char* ws = (char*)d_ws;
  size_t off = 0;
  auto alloc = [&](size_t bytes){ void* p = ws + off; off += (bytes + 255) & ~(size_t)255; return p; };
  int*   flags  = (int*)  alloc(2*4);
  float* no     = (float*)alloc((size_t)NN*4);
  float* ni     = (float*)alloc((size_t)NN*4);
  int*   rowp   = (int*)  alloc((size_t)(NN+1)*4);
  float* t1     = (float*)alloc((size_t)NN*4);
  float* t2     = (float*)alloc((size_t)NN*4);
  int*   perm   = (int*)  alloc((size_t)NB*KEEP*4);
  float* gate   = (float*)alloc((size_t)NB*KEEP*4);
  float* b1c    = (float*)alloc((size_t)D*4);
  float* b2c    = (float*)alloc((size_t)D*4);
  float* sW1c   = (float*)alloc((size_t)D*4);
  float* sW2c   = (float*)alloc((size_t)D*4);
  float* sbc    = (float*)alloc(2*4);
  u16*   W1Th   = (u16*)  alloc((size_t)D*D*2);
  u16*   W1Tl   = (u16*)  alloc((size_t)D*D*2);
  u16*   W2Th   = (u16*)  alloc((size_t)D*D*2);
  u16*   W2Tl   = (u16*)  alloc((size_t)D*D*2);
  int*   csr    = (int*)  alloc((size_t)EDGES*4);
  u16*   Hh     = (u16*)  alloc((size_t)NN*D*2);
  u16*   Hl     = (u16*)  alloc((size_t)NN*D*2);
  float* Y      = (float*)alloc((size_t)NN*D*4);
  float* H      = (float*)alloc((size_t)NN*D*4);
  // Xh/Xl live in H's space (dead until agg mode-1 writes H)
  u16*   Xh     = (u16*)H;
  u16*   Xl     = Xh + (size_t)NN*D;

  detect_kernel   <<<1, 256, 0, stream>>>((const u16*)x, flags);
  graphprep_kernel<<<NB, 512, 0, stream>>>(src, dst, no, ni, rowp, csr);
  bcvt_kernel     <<<1, 512, 0, stream>>>(flags, b1, b2, sW1, sW2, sb1, sb2,
                                          b1c, b2c, sW1c, sW2c, sbc);
  tsplit_kernel   <<<dim3(16,16), dim3(32,8), 0, stream>>>(flags, W1, W1Th, W1Tl);
  tsplit_kernel   <<<dim3(16,16), dim3(32,8), 0, stream>>>(flags, W2, W2Th, W2Tl);
  xsplit_kernel   <<<(NN*D/4)/256, 256, 0, stream>>>(x, flags, Xh, Xl);

  // conv1: Y = (x @ W1) * no ; h1 = relu(agg) -> split bf16 (Hh, Hl)
  gemm_bm  <<<512, 256, 0, stream>>>(Xh, Xl, W1Th, W1Tl, Y, no);
  agg_kernel<<<NN/2, 256, 0, stream>>>(Y, rowp, csr, ni, b1c, nullptr, Hh, Hl,
                                       nullptr, nullptr, nullptr, nullptr, 0);
  // conv2: Y = (h1 @ W2) * no ; h2 = relu(agg) -> f32 H + fused score dots
  gemm_bm  <<<512, 256, 0, stream>>>(Hh, Hl, W2Th, W2Tl, Y, no);
  agg_kernel<<<NN/2, 256, 0, stream>>>(Y, rowp, csr, ni, b2c, H, nullptr, nullptr,
                                       sW1c, sW2c, t1, t2, 1);

  scoretopk_kernel<<<NB, 512, 0, stream>>>(t1, t2, rowp, csr, no, ni, sbc, perm, gate);
  readout_kernel  <<<NB, 256, 0, stream>>>(H, perm, gate, out, out + (size_t)NB*KEEP*D);
}

// Round 11
// 344.967 us; speedup vs baseline: 1.3757x; 1.3757x over previous
//
#include <hip/hip_runtime.h>
#include <math.h>

typedef unsigned short u16;
typedef __attribute__((ext_vector_type(8))) short bf16x8;
typedef __attribute__((ext_vector_type(4))) float f32x4;

#define NN 32768      // total nodes
#define EDGES 524288  // total edges
#define NB 64         // graphs
#define NPG 512       // nodes per graph
#define EPG 8192      // edges per graph (contiguous in src/dst)
#define KEEP 256      // kept per graph
#define D 512         // feature dim

__device__ __forceinline__ float b2f(u16 h){ return __uint_as_float(((unsigned)h)<<16); }
__device__ __forceinline__ u16 f2b(float f){
  unsigned u = __float_as_uint(f);
  unsigned r = u + 0x7FFFu + ((u>>16)&1u);   // RNE
  return (u16)(r>>16);
}

// async global->LDS, 16B per lane (dest must be wave-uniform base + lane*16)
__device__ __forceinline__ void gload16(const void* g, void* l){
  __builtin_amdgcn_global_load_lds((const __attribute__((address_space(1))) void*)g,
                                   (__attribute__((address_space(3))) void*)l, 16, 0, 0);
}

// ---------- dtype detection: are float inputs f32 (flag=1) or bf16 (flag=0)? ----------
__global__ __launch_bounds__(256) void detect_kernel(const u16* __restrict__ xb, int* __restrict__ flags){
  __shared__ int cnt;
  if (threadIdx.x==0) cnt = 0;
  __syncthreads();
  u16 v = xb[threadIdx.x];
  int e = (v>>7)&0xFF;
  if (e > 140) atomicAdd(&cnt, 1);
  __syncthreads();
  if (threadIdx.x==0){ flags[0] = (cnt > 8) ? 1 : 0; flags[1] = 1; }
}

// ---------- fused per-graph preprocessing: degrees, norms, rowp, CSR fill ----------
__global__ __launch_bounds__(512) void graphprep_kernel(
    const int* __restrict__ src, const int* __restrict__ dst,
    float* __restrict__ no, float* __restrict__ ni,
    int* __restrict__ rowp, int* __restrict__ csr)
{
  __shared__ int dego[NPG], degi[NPG], s[NPG], start[NPG], cur[NPG];
  int g = blockIdx.x, n = threadIdx.x;
  dego[n] = 0; degi[n] = 0; cur[n] = 0;
  __syncthreads();
  int ebase = g*EPG;
  #pragma unroll
  for (int i = 0; i < 16; i++){
    int e = ebase + n + i*512;
    atomicAdd(&dego[src[e] & (NPG-1)], 1);
    atomicAdd(&degi[dst[e] & (NPG-1)], 1);
  }
  __syncthreads();
  int di = degi[n];
  s[n] = di;
  __syncthreads();
  for (int off=1; off<NPG; off<<=1){
    int val = (n>=off) ? s[n-off] : 0;
    __syncthreads();
    s[n] += val;
    __syncthreads();
  }
  int excl = s[n] - di;
  start[n] = excl;
  int a = dego[n]; if (a<1) a=1;
  int b = di;      if (b<1) b=1;
  int v = g*NPG + n;
  no[v] = (float)(1.0/sqrt((double)a));
  ni[v] = (float)(1.0/sqrt((double)b));
  rowp[v] = ebase + excl;
  if (g == NB-1 && n == NPG-1) rowp[NN] = EDGES;
  __syncthreads();
  #pragma unroll
  for (int i = 0; i < 16; i++){
    int e = ebase + n + i*512;
    int dl = dst[e] & (NPG-1);
    int pos = atomicAdd(&cur[dl], 1);
    csr[ebase + start[dl] + pos] = src[e];
  }
}

// ---------- small-tensor conversion to canonical f32 ----------
__global__ __launch_bounds__(512) void bcvt_kernel(const int* __restrict__ flags,
    const void* b1, const void* b2, const void* sW1, const void* sW2,
    const void* sb1, const void* sb2,
    float* b1c, float* b2c, float* sW1c, float* sW2c, float* sbc)
{
  int t = threadIdx.x;
  int f = flags[0];
  #define CV(p,i) (f ? ((const float*)(p))[i] : b2f(((const u16*)(p))[i]))
  b1c[t]  = CV(b1, t);
  b2c[t]  = CV(b2, t);
  sW1c[t] = CV(sW1, t);
  sW2c[t] = CV(sW2, t);
  if (t==0){ sbc[0] = CV(sb1,0); sbc[1] = CV(sb2,0); }
  #undef CV
}

// ---------- weight transpose + hi/lo bf16 split ----------
__global__ void tsplit_kernel(const int* __restrict__ flags, const void* __restrict__ W,
                              u16* __restrict__ WTh, u16* __restrict__ WTl){
  __shared__ float tile[32][33];
  int f = flags[0];
  int bx = blockIdx.x*32, by = blockIdx.y*32;
  int tx = threadIdx.x, ty = threadIdx.y; // (32,8)
  #pragma unroll
  for (int i=0;i<4;i++){
    size_t idx = (size_t)(by+ty+i*8)*D + bx+tx;
    tile[ty+i*8][tx] = f ? ((const float*)W)[idx] : b2f(((const u16*)W)[idx]);
  }
  __syncthreads();
  #pragma unroll
  for (int i=0;i<4;i++){
    float v = tile[tx][ty+i*8];
    u16 h = f2b(v);
    size_t o = (size_t)(bx+ty+i*8)*D + by+tx;
    WTh[o] = h;
    WTl[o] = f2b(v - b2f(h));
  }
}

// ---------- x split: f32 (or bf16) -> bf16 hi/lo ----------
__global__ __launch_bounds__(256) void xsplit_kernel(const void* __restrict__ X,
    const int* __restrict__ flags, u16* __restrict__ Xh, u16* __restrict__ Xl)
{
  size_t i = ((size_t)blockIdx.x*256 + threadIdx.x)*4;
  float v0,v1,v2,v3;
  if (flags[0]){
    float4 f = *(const float4*)((const float*)X + i);
    v0=f.x; v1=f.y; v2=f.z; v3=f.w;
  } else {
    ushort4 uv = *(const ushort4*)((const u16*)X + i);
    v0=b2f(uv.x); v1=b2f(uv.y); v2=b2f(uv.z); v3=b2f(uv.w);
  }
  ushort4 hh, hl;
  hh.x=f2b(v0); hl.x=f2b(v0-b2f(hh.x));
  hh.y=f2b(v1); hl.y=f2b(v1-b2f(hh.y));
  hh.z=f2b(v2); hl.z=f2b(v2-b2f(hh.z));
  hh.w=f2b(v3); hl.w=f2b(v3-b2f(hh.w));
  *(ushort4*)(Xh+i) = hh;
  *(ushort4*)(Xl+i) = hl;
}

// ---------------- GEMM: C = (A @ W) * rowscale; A,B pre-split bf16 hi/lo ----------------
// 256x256 tile, 8 waves (2M x 4N), BK=32, double-buffered LDS (128 KB),
// STAGE(next) -> ds_read(cur) -> MFMA -> vmcnt(0) -> barrier (R7/R9 known-good).
// 96 MFMA / K-step / wave. Grid: 256 blocks = 1/CU.

__device__ __forceinline__ void gemm_tile256(int id, int& brow, int& bcol){
  int xcd = id & 7, k = id >> 3;           // k: 0..31
  brow = (xcd + 8*(k >> 1)) * 256;         // both bcol-blocks of a panel -> same XCD
  bcol = (k & 1) * 256;
}

__global__ __launch_bounds__(512, 2) void gemm256(
    const u16* __restrict__ Ahg, const u16* __restrict__ Alg,
    const u16* __restrict__ BTh, const u16* __restrict__ BTl,
    float* __restrict__ C, const float* __restrict__ rowscale)
{
  // [buf][arr: 0=Ah 1=Al 2=Bh 3=Bl][chunk c = q*256+row][8 u16]  (128 KB total)
  __shared__ alignas(16) u16 lds[2][4][8192];
  int t = threadIdx.x;
  int brow, bcol;
  gemm_tile256(blockIdx.x, brow, bcol);
  int wid = t>>6, lane = t&63;
  int wr = wid>>2, wc = wid&3;             // wave grid 2 x 4, wave owns 128x64
  int q = lane>>4, r = lane&15;
  f32x4 acc[8][4] = {};

  // staging: thread covers chunks c0 = wid*128+lane and c1 = c0+64 of every array
  int c0 = wid*128 + lane, c1 = c0 + 64;
  int q0 = c0>>8, r0 = c0&255, q1 = c1>>8, r1 = c1&255;
  const u16* sA0h = Ahg + (size_t)(brow+r0)*D + q0*8;
  const u16* sA1h = Ahg + (size_t)(brow+r1)*D + q1*8;
  const u16* sA0l = Alg + (size_t)(brow+r0)*D + q0*8;
  const u16* sA1l = Alg + (size_t)(brow+r1)*D + q1*8;
  const u16* sB0h = BTh + (size_t)(bcol+r0)*D + q0*8;
  const u16* sB1h = BTh + (size_t)(bcol+r1)*D + q1*8;
  const u16* sB0l = BTl + (size_t)(bcol+r0)*D + q0*8;
  const u16* sB1l = BTl + (size_t)(bcol+r1)*D + q1*8;

  #define STAGEK(B, KT) { int ko = (KT)*32; \
    gload16(sA0h+ko, &lds[B][0][c0*8]); gload16(sA1h+ko, &lds[B][0][c1*8]); \
    gload16(sA0l+ko, &lds[B][1][c0*8]); gload16(sA1l+ko, &lds[B][1][c1*8]); \
    gload16(sB0h+ko, &lds[B][2][c0*8]); gload16(sB1h+ko, &lds[B][2][c1*8]); \
    gload16(sB0l+ko, &lds[B][3][c0*8]); gload16(sB1l+ko, &lds[B][3][c1*8]); }

  STAGEK(0, 0)
  asm volatile("s_waitcnt vmcnt(0)" ::: "memory");
  __syncthreads();
  int cur = 0;
  for (int kt=0; kt<16; kt++){
    if (kt < 15) STAGEK(cur^1, kt+1)
    bf16x8 fbh[4], fbl[4];
    #pragma unroll
    for (int n=0;n<4;n++){
      fbh[n] = *(const bf16x8*)(&lds[cur][2][(q*256 + wc*64 + n*16 + r)*8]);
      fbl[n] = *(const bf16x8*)(&lds[cur][3][(q*256 + wc*64 + n*16 + r)*8]);
    }
    __builtin_amdgcn_s_setprio(1);
    #pragma unroll
    for (int m=0;m<8;m++){
      bf16x8 fah = *(const bf16x8*)(&lds[cur][0][(q*256 + wr*128 + m*16 + r)*8]);
      bf16x8 fal = *(const bf16x8*)(&lds[cur][1][(q*256 + wr*128 + m*16 + r)*8]);
      #pragma unroll
      for (int n=0;n<4;n++){
        acc[m][n] = __builtin_amdgcn_mfma_f32_16x16x32_bf16(fah, fbh[n], acc[m][n], 0,0,0);
        acc[m][n] = __builtin_amdgcn_mfma_f32_16x16x32_bf16(fah, fbl[n], acc[m][n], 0,0,0);
        acc[m][n] = __builtin_amdgcn_mfma_f32_16x16x32_bf16(fal, fbh[n], acc[m][n], 0,0,0);
      }
    }
    __builtin_amdgcn_s_setprio(0);
    asm volatile("s_waitcnt vmcnt(0)" ::: "memory");
    __syncthreads();
    cur ^= 1;
  }
  #undef STAGEK

  #pragma unroll
  for (int m=0;m<8;m++){
    int rowb = brow + wr*128 + m*16 + q*4;
    #pragma unroll
    for (int n=0;n<4;n++){
      int col = bcol + wc*64 + n*16 + r;
      #pragma unroll
      for (int g=0; g<4; g++){
        int row = rowb + g;
        C[(size_t)row*D + col] = acc[m][n][g] * rowscale[row];
      }
    }
  }
}

// -------- edge aggregation: relu( (sum_{u in N(v)} Y[u]) * ni[v] + b ) --------
// 2 nodes/block, 128 threads/node. CSR row hoisted into lane registers, indices via
// shfl; gather unrolled x8 (8 independent L2 accesses in flight). XCD-pinned per graph.
// mode 0: write split bf16 hi/lo.  mode 1: write f32 H + fused score dots.

__global__ __launch_bounds__(256) void agg_kernel(
    const float* __restrict__ Y, const int* __restrict__ rowp,
    const int* __restrict__ csr, const float* __restrict__ ni,
    const float* __restrict__ bias, float* __restrict__ H,
    u16* __restrict__ Hh, u16* __restrict__ Hl,
    const float* __restrict__ sW1, const float* __restrict__ sW2,
    float* __restrict__ t1, float* __restrict__ t2, int mode)
{
  int i = blockIdx.x;
  int xcd = i & 7, j = i >> 3;              // j: 0..2047
  int half = threadIdx.x >> 7;              // node within pair
  int t = threadIdx.x & 127;                // float4 chunk
  int lane = threadIdx.x & 63;
  int v = (xcd + 8*(j >> 8))*NPG + ((j & 255)*2 + half);
  int rp0 = rowp[v], rp1 = rowp[v+1];
  const float4* Yv = (const float4*)Y;
  float4 a = {0.f,0.f,0.f,0.f};
  for (int eb = rp0; eb < rp1; eb += 64){
    int cnt = rp1 - eb; if (cnt > 64) cnt = 64;
    int idx = (lane < cnt) ? csr[eb + lane] : 0;
    int e = 0;
    for (; e+8 <= cnt; e += 8){
      int u0 = __shfl(idx, e),   u1 = __shfl(idx, e+1);
      int u2 = __shfl(idx, e+2), u3 = __shfl(idx, e+3);
      int u4 = __shfl(idx, e+4), u5 = __shfl(idx, e+5);
      int u6 = __shfl(idx, e+6), u7 = __shfl(idx, e+7);
      float4 y0 = Yv[(size_t)u0*128 + t];
      float4 y1 = Yv[(size_t)u1*128 + t];
      float4 y2 = Yv[(size_t)u2*128 + t];
      float4 y3 = Yv[(size_t)u3*128 + t];
      float4 y4 = Yv[(size_t)u4*128 + t];
      float4 y5 = Yv[(size_t)u5*128 + t];
      float4 y6 = Yv[(size_t)u6*128 + t];
      float4 y7 = Yv[(size_t)u7*128 + t];
      a.x += ((y0.x + y1.x) + (y2.x + y3.x)) + ((y4.x + y5.x) + (y6.x + y7.x));
      a.y += ((y0.y + y1.y) + (y2.y + y3.y)) + ((y4.y + y5.y) + (y6.y + y7.y));
      a.z += ((y0.z + y1.z) + (y2.z + y3.z)) + ((y4.z + y5.z) + (y6.z + y7.z));
      a.w += ((y0.w + y1.w) + (y2.w + y3.w)) + ((y4.w + y5.w) + (y6.w + y7.w));
    }
    for (; e+4 <= cnt; e += 4){
      int u0 = __shfl(idx, e),   u1 = __shfl(idx, e+1);
      int u2 = __shfl(idx, e+2), u3 = __shfl(idx, e+3);
      float4 y0 = Yv[(size_t)u0*128 + t];
      float4 y1 = Yv[(size_t)u1*128 + t];
      float4 y2 = Yv[(size_t)u2*128 + t];
      float4 y3 = Yv[(size_t)u3*128 + t];
      a.x += (y0.x + y1.x) + (y2.x + y3.x);
      a.y += (y0.y + y1.y) + (y2.y + y3.y);
      a.z += (y0.z + y1.z) + (y2.z + y3.z);
      a.w += (y0.w + y1.w) + (y2.w + y3.w);
    }
    for (; e < cnt; e++){
      int u = __shfl(idx, e);
      float4 y = Yv[(size_t)u*128 + t];
      a.x += y.x; a.y += y.y; a.z += y.z; a.w += y.w;
    }
  }
  float w = ni[v];
  float4 b4 = ((const float4*)bias)[t];
  float4 rr;
  rr.x = fmaxf(a.x*w + b4.x, 0.f);
  rr.y = fmaxf(a.y*w + b4.y, 0.f);
  rr.z = fmaxf(a.z*w + b4.z, 0.f);
  rr.w = fmaxf(a.w*w + b4.w, 0.f);

  if (mode == 0){
    ushort4 hh, hl;
    hh.x = f2b(rr.x); hl.x = f2b(rr.x - b2f(hh.x));
    hh.y = f2b(rr.y); hl.y = f2b(rr.y - b2f(hh.y));
    hh.z = f2b(rr.z); hl.z = f2b(rr.z - b2f(hh.z));
    hh.w = f2b(rr.w); hl.w = f2b(rr.w - b2f(hh.w));
    *(ushort4*)(Hh + (size_t)v*D + t*4) = hh;
    *(ushort4*)(Hl + (size_t)v*D + t*4) = hl;
  } else {
    ((float4*)H)[(size_t)v*128 + t] = rr;
    float4 w1 = ((const float4*)sW1)[t];
    float4 w2 = ((const float4*)sW2)[t];
    float p1 = rr.x*w1.x + rr.y*w1.y + rr.z*w1.z + rr.w*w1.w;
    float p2 = rr.x*w2.x + rr.y*w2.y + rr.z*w2.z + rr.w*w2.w;
    #pragma unroll
    for (int off=32; off>=1; off>>=1){
      p1 += __shfl_xor(p1, off);
      p2 += __shfl_xor(p2, off);
    }
    __shared__ float red1[4], red2[4];
    int wv = threadIdx.x>>6;
    if (lane==0){ red1[wv] = p1; red2[wv] = p2; }
    __syncthreads();
    if (t==0){
      t1[v] = red1[half*2] + red1[half*2+1];
      t2[v] = red2[half*2] + red2[half*2+1];
    }
  }
}

// -------- fused score aggregation + per-graph stable top-K --------

__global__ __launch_bounds__(512) void scoretopk_kernel(
    const float* __restrict__ t1, const float* __restrict__ t2,
    const int* __restrict__ rowp, const int* __restrict__ csr,
    const float* __restrict__ no, const float* __restrict__ ni,
    const float* __restrict__ sbc,
    int* __restrict__ perm, float* __restrict__ gate)
{
  __shared__ unsigned long long key[NPG];
  __shared__ float scl[NPG];
  int g = blockIdx.x, n = threadIdx.x;
  int v = g*NPG + n;
  double a1 = 0.0, a2 = 0.0;
  int rp1 = rowp[v+1];
  for (int e=rowp[v]; e<rp1; e++){
    int u = csr[e];
    double w = (double)no[u];
    a1 += (double)t1[u]*w;
    a2 += (double)t2[u]*w;
  }
  double wi = (double)ni[v];
  double s1 = a1*wi + (double)sbc[0];
  double s2 = a2*wi + (double)sbc[1];
  float s = (float)(0.5*(s1+s2));
  scl[n] = s;
  unsigned u = __float_as_uint(s);
  u = (u & 0x80000000u) ? ~u : (u | 0x80000000u);  // order-preserving (ascending)
  unsigned kd = ~u;                                 // descending score
  key[n] = ((unsigned long long)kd<<32) | (unsigned)n;
  __syncthreads();
  for (int k=2; k<=NPG; k<<=1){
    for (int j=k>>1; j>0; j>>=1){
      int ixj = n ^ j;
      if (ixj > n){
        unsigned long long a = key[n], b = key[ixj];
        bool up = ((n & k) == 0);
        if ((a > b) == up){ key[n] = b; key[ixj] = a; }
      }
      __syncthreads();
    }
  }
  if (n < KEEP){
    unsigned long long e = key[n];
    int idx = (int)(e & 0xFFFFFFFFull);
    perm[g*KEEP + n] = g*NPG + idx;
    gate[g*KEEP + n] = tanhf(scl[idx]);
  }
}

// -------- fused gated gather + readout (pooled rows + max||sum), f32 outputs --------

__global__ __launch_bounds__(256) void readout_kernel(const float* __restrict__ H,
    const int* __restrict__ perm, const float* __restrict__ gate,
    float* __restrict__ outp, float* __restrict__ outg)
{
  __shared__ int sp[KEEP];
  __shared__ float sg[KEEP];
  __shared__ float4 redmx[128], redsm[128];
  int g = blockIdx.x, t = threadIdx.x;
  int half = t >> 7, c = t & 127;
  sp[t] = perm[g*KEEP + t];
  sg[t] = gate[g*KEEP + t];
  __syncthreads();
  float4 mx = {-INFINITY,-INFINITY,-INFINITY,-INFINITY};
  float4 sm = {0.f,0.f,0.f,0.f};
  for (int rI = half; rI < KEEP; rI += 2){
    int node = sp[rI];
    float gt = sg[rI];
    float4 y = ((const float4*)(H + (size_t)node*D))[c];
    float4 vv;
    vv.x = y.x*gt; vv.y = y.y*gt; vv.z = y.z*gt; vv.w = y.w*gt;
    ((float4*)(outp + (size_t)(g*KEEP + rI)*D))[c] = vv;
    mx.x = fmaxf(mx.x, vv.x); mx.y = fmaxf(mx.y, vv.y);
    mx.z = fmaxf(mx.z, vv.z); mx.w = fmaxf(mx.w, vv.w);
    sm.x += vv.x; sm.y += vv.y; sm.z += vv.z; sm.w += vv.w;
  }
  if (half == 1){ redmx[c] = mx; redsm[c] = sm; }
  __syncthreads();
  if (half == 0){
    float4 omx = redmx[c], osm = redsm[c];
    mx.x = fmaxf(mx.x, omx.x); mx.y = fmaxf(mx.y, omx.y);
    mx.z = fmaxf(mx.z, omx.z); mx.w = fmaxf(mx.w, omx.w);
    sm.x += osm.x; sm.y += osm.y; sm.z += osm.z; sm.w += osm.w;
    ((float4*)(outg + (size_t)g*1024))[c] = mx;
    ((float4*)(outg + (size_t)g*1024 + 512))[c] = sm;
  }
}

// ---------------- launch ----------------

extern "C" void kernel_launch(void* const* d_in, const int* in_sizes, int n_in,
                              void* d_out, int out_size, void* d_ws, size_t ws_size,
                              hipStream_t stream)
{
  (void)in_sizes; (void)n_in; (void)out_size; (void)ws_size;
  const void* x   = d_in[0];
  const int* src  = (const int*)d_in[1];
  const int* dst  = (const int*)d_in[2];
  const void* W1  = d_in[3];
  const void* b1  = d_in[4];
  const void* W2  = d_in[5];
  const void* b2  = d_in[6];
  const void* sW1 = d_in[7];
  const void* sb1 = d_in[8];
  const void* sW2 = d_in[9];
  const void* sb2 = d_in[10];
  float* out = (float*)d_out;

  char* ws = (char*)d_ws;
  size_t off = 0;
  auto alloc = [&](size_t bytes){ void* p = ws + off; off += (bytes + 255) & ~(size_t)255; return p; };
  int*   flags  = (int*)  alloc(2*4);
  float* no     = (float*)alloc((size_t)NN*4);
  float* ni     = (float*)alloc((size_t)NN*4);
  int*   rowp   = (int*)  alloc((size_t)(NN+1)*4);
  float* t1     = (float*)alloc((size_t)NN*4);
  float* t2     = (float*)alloc((size_t)NN*4);
  int*   perm   = (int*)  alloc((size_t)NB*KEEP*4);
  float* gate   = (float*)alloc((size_t)NB*KEEP*4);
  float* b1c    = (float*)alloc((size_t)D*4);
  float* b2c    = (float*)alloc((size_t)D*4);
  float* sW1c   = (float*)alloc((size_t)D*4);
  float* sW2c   = (float*)alloc((size_t)D*4);
  float* sbc    = (float*)alloc(2*4);
  u16*   W1Th   = (u16*)  alloc((size_t)D*D*2);
  u16*   W1Tl   = (u16*)  alloc((size_t)D*D*2);
  u16*   W2Th   = (u16*)  alloc((size_t)D*D*2);
  u16*   W2Tl   = (u16*)  alloc((size_t)D*D*2);
  int*   csr    = (int*)  alloc((size_t)EDGES*4);
  u16*   Hh     = (u16*)  alloc((size_t)NN*D*2);
  u16*   Hl     = (u16*)  alloc((size_t)NN*D*2);
  float* Y      = (float*)alloc((size_t)NN*D*4);
  float* H      = (float*)alloc((size_t)NN*D*4);
  // Xh/Xl live in H's space (dead until agg mode-1 writes H)
  u16*   Xh     = (u16*)H;
  u16*   Xl     = Xh + (size_t)NN*D;

  detect_kernel   <<<1, 256, 0, stream>>>((const u16*)x, flags);
  graphprep_kernel<<<NB, 512, 0, stream>>>(src, dst, no, ni, rowp, csr);
  bcvt_kernel     <<<1, 512, 0, stream>>>(flags, b1, b2, sW1, sW2, sb1, sb2,
                                          b1c, b2c, sW1c, sW2c, sbc);
  tsplit_kernel   <<<dim3(16,16), dim3(32,8), 0, stream>>>(flags, W1, W1Th, W1Tl);
  tsplit_kernel   <<<dim3(16,16), dim3(32,8), 0, stream>>>(flags, W2, W2Th, W2Tl);
  xsplit_kernel   <<<(NN*D/4)/256, 256, 0, stream>>>(x, flags, Xh, Xl);

  // conv1: Y = (x @ W1) * no ; h1 = relu(agg) -> split bf16 (Hh, Hl)
  gemm256<<<256, 512, 0, stream>>>(Xh, Xl, W1Th, W1Tl, Y, no);
  agg_kernel<<<NN/2, 256, 0, stream>>>(Y, rowp, csr, ni, b1c, nullptr, Hh, Hl,
                                       nullptr, nullptr, nullptr, nullptr, 0);
  // conv2: Y = (h1 @ W2) * no ; h2 = relu(agg) -> f32 H + fused score dots
  gemm256<<<256, 512, 0, stream>>>(Hh, Hl, W2Th, W2Tl, Y, no);
  agg_kernel<<<NN/2, 256, 0, stream>>>(Y, rowp, csr, ni, b2c, H, nullptr, nullptr,
                                       sW1c, sW2c, t1, t2, 1);

  scoretopk_kernel<<<NB, 512, 0, stream>>>(t1, t2, rowp, csr, no, ni, sbc, perm, gate);
  readout_kernel  <<<NB, 256, 0, stream>>>(H, perm, gate, out, out + (size_t)NB*KEEP*D);
}

// Round 12
// 312.857 us; speedup vs baseline: 1.5169x; 1.1026x over previous
//
#include <hip/hip_runtime.h>
#include <math.h>

typedef unsigned short u16;
typedef __attribute__((ext_vector_type(8))) short bf16x8;
typedef __attribute__((ext_vector_type(4))) float f32x4;

#define NN 32768      // total nodes
#define EDGES 524288  // total edges
#define NB 64         // graphs
#define NPG 512       // nodes per graph
#define EPG 8192      // edges per graph (contiguous in src/dst)
#define KEEP 256      // kept per graph
#define D 512         // feature dim

__device__ __forceinline__ float b2f(u16 h){ return __uint_as_float(((unsigned)h)<<16); }
__device__ __forceinline__ u16 f2b(float f){
  unsigned u = __float_as_uint(f);
  unsigned r = u + 0x7FFFu + ((u>>16)&1u);   // RNE
  return (u16)(r>>16);
}

// async global->LDS, 16B per lane (dest must be wave-uniform base + lane*16)
__device__ __forceinline__ void gload16(const void* g, void* l){
  __builtin_amdgcn_global_load_lds((const __attribute__((address_space(1))) void*)g,
                                   (__attribute__((address_space(3))) void*)l, 16, 0, 0);
}

// ---- inline dtype flag: 1 if x is f32, 0 if bf16 (sample first 128 u16s) ----
// f32 buffers read as u16 expose random mantissa halves -> ~45% have exp>140;
// bf16 N(0,1) data never does. Wave 0 reduces, LDS-broadcasts to the block.
__device__ __forceinline__ int flag_f32(const u16* __restrict__ xb, int tid){
  __shared__ int fl;
  if (tid < 64){
    u16 v0 = xb[tid*2], v1 = xb[tid*2+1];
    int c = ((((v0>>7)&0xFF) > 140) ? 1 : 0) + ((((v1>>7)&0xFF) > 140) ? 1 : 0);
    #pragma unroll
    for (int o=32; o>=1; o>>=1) c += __shfl_xor(c, o);
    if (tid == 0) fl = (c > 8) ? 1 : 0;
  }
  __syncthreads();
  return fl;
}

// ---------- fused per-graph preprocessing: degrees, norms, rowp, CSR fill ----------
__global__ __launch_bounds__(512) void graphprep_kernel(
    const int* __restrict__ src, const int* __restrict__ dst,
    float* __restrict__ no, float* __restrict__ ni,
    int* __restrict__ rowp, int* __restrict__ csr)
{
  __shared__ int dego[NPG], degi[NPG], s[NPG], start[NPG], cur[NPG];
  int g = blockIdx.x, n = threadIdx.x;
  dego[n] = 0; degi[n] = 0; cur[n] = 0;
  __syncthreads();
  int ebase = g*EPG;
  #pragma unroll
  for (int i = 0; i < 16; i++){
    int e = ebase + n + i*512;
    atomicAdd(&dego[src[e] & (NPG-1)], 1);
    atomicAdd(&degi[dst[e] & (NPG-1)], 1);
  }
  __syncthreads();
  int di = degi[n];
  s[n] = di;
  __syncthreads();
  for (int off=1; off<NPG; off<<=1){
    int val = (n>=off) ? s[n-off] : 0;
    __syncthreads();
    s[n] += val;
    __syncthreads();
  }
  int excl = s[n] - di;
  start[n] = excl;
  int a = dego[n]; if (a<1) a=1;
  int b = di;      if (b<1) b=1;
  int v = g*NPG + n;
  no[v] = (float)(1.0/sqrt((double)a));
  ni[v] = (float)(1.0/sqrt((double)b));
  rowp[v] = ebase + excl;
  if (g == NB-1 && n == NPG-1) rowp[NN] = EDGES;
  __syncthreads();
  #pragma unroll
  for (int i = 0; i < 16; i++){
    int e = ebase + n + i*512;
    int dl = dst[e] & (NPG-1);
    int pos = atomicAdd(&cur[dl], 1);
    csr[ebase + start[dl] + pos] = src[e];
  }
}

// ---------- small-tensor conversion to canonical f32 ----------
__global__ __launch_bounds__(512) void bcvt_kernel(const u16* __restrict__ xb,
    const void* b1, const void* b2, const void* sW1, const void* sW2,
    const void* sb1, const void* sb2,
    float* b1c, float* b2c, float* sW1c, float* sW2c, float* sbc)
{
  int t = threadIdx.x;
  int f = flag_f32(xb, t);
  #define CV(p,i) (f ? ((const float*)(p))[i] : b2f(((const u16*)(p))[i]))
  b1c[t]  = CV(b1, t);
  b2c[t]  = CV(b2, t);
  sW1c[t] = CV(sW1, t);
  sW2c[t] = CV(sW2, t);
  if (t==0){ sbc[0] = CV(sb1,0); sbc[1] = CV(sb2,0); }
  #undef CV
}

// ---------- weight transpose + hi/lo bf16 split; z selects W1/W2 ----------
__global__ void tsplit_kernel(const u16* __restrict__ xb,
                              const void* __restrict__ W1, const void* __restrict__ W2,
                              u16* __restrict__ W1Th, u16* __restrict__ W1Tl,
                              u16* __restrict__ W2Th, u16* __restrict__ W2Tl){
  __shared__ float tile[32][33];
  int tid = threadIdx.x + threadIdx.y*32;
  int f = flag_f32(xb, tid);
  const void* W = blockIdx.z ? W2 : W1;
  u16* WTh = blockIdx.z ? W2Th : W1Th;
  u16* WTl = blockIdx.z ? W2Tl : W1Tl;
  int bx = blockIdx.x*32, by = blockIdx.y*32;
  int tx = threadIdx.x, ty = threadIdx.y; // (32,8)
  #pragma unroll
  for (int i=0;i<4;i++){
    size_t idx = (size_t)(by+ty+i*8)*D + bx+tx;
    tile[ty+i*8][tx] = f ? ((const float*)W)[idx] : b2f(((const u16*)W)[idx]);
  }
  __syncthreads();
  #pragma unroll
  for (int i=0;i<4;i++){
    float v = tile[tx][ty+i*8];
    u16 h = f2b(v);
    size_t o = (size_t)(bx+ty+i*8)*D + by+tx;
    WTh[o] = h;
    WTl[o] = f2b(v - b2f(h));
  }
}

// ---------- x split: f32 (or bf16) -> bf16 hi/lo (grid-stride) ----------
__global__ __launch_bounds__(256) void xsplit_kernel(const void* __restrict__ X,
    u16* __restrict__ Xh, u16* __restrict__ Xl)
{
  int f = flag_f32((const u16*)X, threadIdx.x);
  size_t stride = (size_t)gridDim.x*256*4;
  for (size_t i = ((size_t)blockIdx.x*256 + threadIdx.x)*4; i < (size_t)NN*D; i += stride){
    float v0,v1,v2,v3;
    if (f){
      float4 fv = *(const float4*)((const float*)X + i);
      v0=fv.x; v1=fv.y; v2=fv.z; v3=fv.w;
    } else {
      ushort4 uv = *(const ushort4*)((const u16*)X + i);
      v0=b2f(uv.x); v1=b2f(uv.y); v2=b2f(uv.z); v3=b2f(uv.w);
    }
    ushort4 hh, hl;
    hh.x=f2b(v0); hl.x=f2b(v0-b2f(hh.x));
    hh.y=f2b(v1); hl.y=f2b(v1-b2f(hh.y));
    hh.z=f2b(v2); hl.z=f2b(v2-b2f(hh.z));
    hh.w=f2b(v3); hl.w=f2b(v3-b2f(hh.w));
    *(ushort4*)(Xh+i) = hh;
    *(ushort4*)(Xl+i) = hl;
  }
}

// ---------------- GEMM: C = (A @ W) * rowscale; A,B pre-split bf16 hi/lo ----------------
// 256x256 tile, 8 waves (2M x 4N), BK=32, double-buffered LDS (128 KB),
// STAGE(next) -> ds_read(cur) -> MFMA -> vmcnt(0) -> barrier (R7/R9/R11 known-good).

__device__ __forceinline__ void gemm_tile256(int id, int& brow, int& bcol){
  int xcd = id & 7, k = id >> 3;           // k: 0..31
  brow = (xcd + 8*(k >> 1)) * 256;         // both bcol-blocks of a panel -> same XCD
  bcol = (k & 1) * 256;
}

__global__ __launch_bounds__(512, 2) void gemm256(
    const u16* __restrict__ Ahg, const u16* __restrict__ Alg,
    const u16* __restrict__ BTh, const u16* __restrict__ BTl,
    float* __restrict__ C, const float* __restrict__ rowscale)
{
  __shared__ alignas(16) u16 lds[2][4][8192];
  int t = threadIdx.x;
  int brow, bcol;
  gemm_tile256(blockIdx.x, brow, bcol);
  int wid = t>>6, lane = t&63;
  int wr = wid>>2, wc = wid&3;             // wave grid 2 x 4, wave owns 128x64
  int q = lane>>4, r = lane&15;
  f32x4 acc[8][4] = {};

  int c0 = wid*128 + lane, c1 = c0 + 64;
  int q0 = c0>>8, r0 = c0&255, q1 = c1>>8, r1 = c1&255;
  const u16* sA0h = Ahg + (size_t)(brow+r0)*D + q0*8;
  const u16* sA1h = Ahg + (size_t)(brow+r1)*D + q1*8;
  const u16* sA0l = Alg + (size_t)(brow+r0)*D + q0*8;
  const u16* sA1l = Alg + (size_t)(brow+r1)*D + q1*8;
  const u16* sB0h = BTh + (size_t)(bcol+r0)*D + q0*8;
  const u16* sB1h = BTh + (size_t)(bcol+r1)*D + q1*8;
  const u16* sB0l = BTl + (size_t)(bcol+r0)*D + q0*8;
  const u16* sB1l = BTl + (size_t)(bcol+r1)*D + q1*8;

  #define STAGEK(B, KT) { int ko = (KT)*32; \
    gload16(sA0h+ko, &lds[B][0][c0*8]); gload16(sA1h+ko, &lds[B][0][c1*8]); \
    gload16(sA0l+ko, &lds[B][1][c0*8]); gload16(sA1l+ko, &lds[B][1][c1*8]); \
    gload16(sB0h+ko, &lds[B][2][c0*8]); gload16(sB1h+ko, &lds[B][2][c1*8]); \
    gload16(sB0l+ko, &lds[B][3][c0*8]); gload16(sB1l+ko, &lds[B][3][c1*8]); }

  STAGEK(0, 0)
  asm volatile("s_waitcnt vmcnt(0)" ::: "memory");
  __syncthreads();
  int cur = 0;
  for (int kt=0; kt<16; kt++){
    if (kt < 15) STAGEK(cur^1, kt+1)
    bf16x8 fbh[4], fbl[4];
    #pragma unroll
    for (int n=0;n<4;n++){
      fbh[n] = *(const bf16x8*)(&lds[cur][2][(q*256 + wc*64 + n*16 + r)*8]);
      fbl[n] = *(const bf16x8*)(&lds[cur][3][(q*256 + wc*64 + n*16 + r)*8]);
    }
    __builtin_amdgcn_s_setprio(1);
    #pragma unroll
    for (int m=0;m<8;m++){
      bf16x8 fah = *(const bf16x8*)(&lds[cur][0][(q*256 + wr*128 + m*16 + r)*8]);
      bf16x8 fal = *(const bf16x8*)(&lds[cur][1][(q*256 + wr*128 + m*16 + r)*8]);
      #pragma unroll
      for (int n=0;n<4;n++){
        acc[m][n] = __builtin_amdgcn_mfma_f32_16x16x32_bf16(fah, fbh[n], acc[m][n], 0,0,0);
        acc[m][n] = __builtin_amdgcn_mfma_f32_16x16x32_bf16(fah, fbl[n], acc[m][n], 0,0,0);
        acc[m][n] = __builtin_amdgcn_mfma_f32_16x16x32_bf16(fal, fbh[n], acc[m][n], 0,0,0);
      }
    }
    __builtin_amdgcn_s_setprio(0);
    asm volatile("s_waitcnt vmcnt(0)" ::: "memory");
    __syncthreads();
    cur ^= 1;
  }
  #undef STAGEK

  #pragma unroll
  for (int m=0;m<8;m++){
    int rowb = brow + wr*128 + m*16 + q*4;
    #pragma unroll
    for (int n=0;n<4;n++){
      int col = bcol + wc*64 + n*16 + r;
      #pragma unroll
      for (int g=0; g<4; g++){
        int row = rowb + g;
        C[(size_t)row*D + col] = acc[m][n][g] * rowscale[row];
      }
    }
  }
}

// -------- edge aggregation: relu( (sum_{u in N(v)} Y[u]) * ni[v] + b ) --------
// mode 0: write split bf16 hi/lo (Hh, Hl) for conv2's A.
// mode 1: write bf16 H (Hb) + fused f32 score dots (t1,t2 from PRE-rounding value).

__global__ __launch_bounds__(256) void agg_kernel(
    const float* __restrict__ Y, const int* __restrict__ rowp,
    const int* __restrict__ csr, const float* __restrict__ ni,
    const float* __restrict__ bias,
    u16* __restrict__ Hh, u16* __restrict__ Hl,
    const float* __restrict__ sW1, const float* __restrict__ sW2,
    float* __restrict__ t1, float* __restrict__ t2, int mode)
{
  int i = blockIdx.x;
  int xcd = i & 7, j = i >> 3;              // j: 0..2047
  int half = threadIdx.x >> 7;              // node within pair
  int t = threadIdx.x & 127;                // float4 chunk
  int lane = threadIdx.x & 63;
  int v = (xcd + 8*(j >> 8))*NPG + ((j & 255)*2 + half);
  int rp0 = rowp[v], rp1 = rowp[v+1];
  const float4* Yv = (const float4*)Y;
  float4 a = {0.f,0.f,0.f,0.f};
  for (int eb = rp0; eb < rp1; eb += 64){
    int cnt = rp1 - eb; if (cnt > 64) cnt = 64;
    int idx = (lane < cnt) ? csr[eb + lane] : 0;
    int e = 0;
    for (; e+8 <= cnt; e += 8){
      int u0 = __shfl(idx, e),   u1 = __shfl(idx, e+1);
      int u2 = __shfl(idx, e+2), u3 = __shfl(idx, e+3);
      int u4 = __shfl(idx, e+4), u5 = __shfl(idx, e+5);
      int u6 = __shfl(idx, e+6), u7 = __shfl(idx, e+7);
      float4 y0 = Yv[(size_t)u0*128 + t];
      float4 y1 = Yv[(size_t)u1*128 + t];
      float4 y2 = Yv[(size_t)u2*128 + t];
      float4 y3 = Yv[(size_t)u3*128 + t];
      float4 y4 = Yv[(size_t)u4*128 + t];
      float4 y5 = Yv[(size_t)u5*128 + t];
      float4 y6 = Yv[(size_t)u6*128 + t];
      float4 y7 = Yv[(size_t)u7*128 + t];
      a.x += ((y0.x + y1.x) + (y2.x + y3.x)) + ((y4.x + y5.x) + (y6.x + y7.x));
      a.y += ((y0.y + y1.y) + (y2.y + y3.y)) + ((y4.y + y5.y) + (y6.y + y7.y));
      a.z += ((y0.z + y1.z) + (y2.z + y3.z)) + ((y4.z + y5.z) + (y6.z + y7.z));
      a.w += ((y0.w + y1.w) + (y2.w + y3.w)) + ((y4.w + y5.w) + (y6.w + y7.w));
    }
    for (; e+4 <= cnt; e += 4){
      int u0 = __shfl(idx, e),   u1 = __shfl(idx, e+1);
      int u2 = __shfl(idx, e+2), u3 = __shfl(idx, e+3);
      float4 y0 = Yv[(size_t)u0*128 + t];
      float4 y1 = Yv[(size_t)u1*128 + t];
      float4 y2 = Yv[(size_t)u2*128 + t];
      float4 y3 = Yv[(size_t)u3*128 + t];
      a.x += (y0.x + y1.x) + (y2.x + y3.x);
      a.y += (y0.y + y1.y) + (y2.y + y3.y);
      a.z += (y0.z + y1.z) + (y2.z + y3.z);
      a.w += (y0.w + y1.w) + (y2.w + y3.w);
    }
    for (; e < cnt; e++){
      int u = __shfl(idx, e);
      float4 y = Yv[(size_t)u*128 + t];
      a.x += y.x; a.y += y.y; a.z += y.z; a.w += y.w;
    }
  }
  float w = ni[v];
  float4 b4 = ((const float4*)bias)[t];
  float4 rr;
  rr.x = fmaxf(a.x*w + b4.x, 0.f);
  rr.y = fmaxf(a.y*w + b4.y, 0.f);
  rr.z = fmaxf(a.z*w + b4.z, 0.f);
  rr.w = fmaxf(a.w*w + b4.w, 0.f);

  if (mode == 0){
    ushort4 hh, hl;
    hh.x = f2b(rr.x); hl.x = f2b(rr.x - b2f(hh.x));
    hh.y = f2b(rr.y); hl.y = f2b(rr.y - b2f(hh.y));
    hh.z = f2b(rr.z); hl.z = f2b(rr.z - b2f(hh.z));
    hh.w = f2b(rr.w); hl.w = f2b(rr.w - b2f(hh.w));
    *(ushort4*)(Hh + (size_t)v*D + t*4) = hh;
    *(ushort4*)(Hl + (size_t)v*D + t*4) = hl;
  } else {
    ushort4 hb;
    hb.x = f2b(rr.x); hb.y = f2b(rr.y); hb.z = f2b(rr.z); hb.w = f2b(rr.w);
    *(ushort4*)(Hh + (size_t)v*D + t*4) = hb;   // Hh doubles as bf16 H here
    float4 w1 = ((const float4*)sW1)[t];
    float4 w2 = ((const float4*)sW2)[t];
    float p1 = rr.x*w1.x + rr.y*w1.y + rr.z*w1.z + rr.w*w1.w;
    float p2 = rr.x*w2.x + rr.y*w2.y + rr.z*w2.z + rr.w*w2.w;
    #pragma unroll
    for (int off=32; off>=1; off>>=1){
      p1 += __shfl_xor(p1, off);
      p2 += __shfl_xor(p2, off);
    }
    __shared__ float red1[4], red2[4];
    int wv = threadIdx.x>>6;
    if (lane==0){ red1[wv] = p1; red2[wv] = p2; }
    __syncthreads();
    if (t==0){
      t1[v] = red1[half*2] + red1[half*2+1];
      t2[v] = red2[half*2] + red2[half*2+1];
    }
  }
}

// -------- fused score agg + stable top-K + gated gather + readout (per graph) --------

__global__ __launch_bounds__(512) void scoretopk_readout_kernel(
    const float* __restrict__ t1, const float* __restrict__ t2,
    const int* __restrict__ rowp, const int* __restrict__ csr,
    const float* __restrict__ no, const float* __restrict__ ni,
    const float* __restrict__ sbc, const u16* __restrict__ Hb,
    float* __restrict__ outp, float* __restrict__ outg)
{
  __shared__ unsigned long long key[NPG];
  __shared__ float scl[NPG];
  __shared__ int sp[KEEP];
  __shared__ float sg[KEEP];
  __shared__ float4 redmx[3*128], redsm[3*128];
  int g = blockIdx.x, n = threadIdx.x;
  int v = g*NPG + n;
  // scores (f64, matches np ordering)
  double a1 = 0.0, a2 = 0.0;
  int rp1 = rowp[v+1];
  for (int e=rowp[v]; e<rp1; e++){
    int u = csr[e];
    double w = (double)no[u];
    a1 += (double)t1[u]*w;
    a2 += (double)t2[u]*w;
  }
  double wi = (double)ni[v];
  double s1 = a1*wi + (double)sbc[0];
  double s2 = a2*wi + (double)sbc[1];
  float s = (float)(0.5*(s1+s2));
  scl[n] = s;
  unsigned u = __float_as_uint(s);
  u = (u & 0x80000000u) ? ~u : (u | 0x80000000u);  // order-preserving (ascending)
  unsigned kd = ~u;                                 // descending score
  key[n] = ((unsigned long long)kd<<32) | (unsigned)n;
  __syncthreads();
  for (int k=2; k<=NPG; k<<=1){
    for (int j=k>>1; j>0; j>>=1){
      int ixj = n ^ j;
      if (ixj > n){
        unsigned long long a = key[n], b = key[ixj];
        bool up = ((n & k) == 0);
        if ((a > b) == up){ key[n] = b; key[ixj] = a; }
      }
      __syncthreads();
    }
  }
  if (n < KEEP){
    int idx = (int)(key[n] & 0xFFFFFFFFull);
    sp[n] = g*NPG + idx;
    sg[n] = tanhf(scl[idx]);
  }
  __syncthreads();
  // readout: quarter q handles ranks q, q+4, ...; c = float4 chunk
  int quarter = n >> 7, c = n & 127;
  float4 mx = {-INFINITY,-INFINITY,-INFINITY,-INFINITY};
  float4 sm = {0.f,0.f,0.f,0.f};
  for (int rI = quarter; rI < KEEP; rI += 4){
    int node = sp[rI];
    float gt = sg[rI];
    ushort4 hv = *(const ushort4*)(Hb + (size_t)node*D + c*4);
    float4 vv;
    vv.x = b2f(hv.x)*gt; vv.y = b2f(hv.y)*gt;
    vv.z = b2f(hv.z)*gt; vv.w = b2f(hv.w)*gt;
    ((float4*)(outp + (size_t)(g*KEEP + rI)*D))[c] = vv;
    mx.x = fmaxf(mx.x, vv.x); mx.y = fmaxf(mx.y, vv.y);
    mx.z = fmaxf(mx.z, vv.z); mx.w = fmaxf(mx.w, vv.w);
    sm.x += vv.x; sm.y += vv.y; sm.z += vv.z; sm.w += vv.w;
  }
  if (quarter > 0){ redmx[(quarter-1)*128 + c] = mx; redsm[(quarter-1)*128 + c] = sm; }
  __syncthreads();
  if (quarter == 0){
    #pragma unroll
    for (int qq=0; qq<3; qq++){
      float4 omx = redmx[qq*128 + c], osm = redsm[qq*128 + c];
      mx.x = fmaxf(mx.x, omx.x); mx.y = fmaxf(mx.y, omx.y);
      mx.z = fmaxf(mx.z, omx.z); mx.w = fmaxf(mx.w, omx.w);
      sm.x += osm.x; sm.y += osm.y; sm.z += osm.z; sm.w += osm.w;
    }
    ((float4*)(outg + (size_t)g*1024))[c] = mx;
    ((float4*)(outg + (size_t)g*1024 + 512))[c] = sm;
  }
}

// ---------------- launch ----------------

extern "C" void kernel_launch(void* const* d_in, const int* in_sizes, int n_in,
                              void* d_out, int out_size, void* d_ws, size_t ws_size,
                              hipStream_t stream)
{
  (void)in_sizes; (void)n_in; (void)out_size; (void)ws_size;
  const void* x   = d_in[0];
  const int* src  = (const int*)d_in[1];
  const int* dst  = (const int*)d_in[2];
  const void* W1  = d_in[3];
  const void* b1  = d_in[4];
  const void* W2  = d_in[5];
  const void* b2  = d_in[6];
  const void* sW1 = d_in[7];
  const void* sb1 = d_in[8];
  const void* sW2 = d_in[9];
  const void* sb2 = d_in[10];
  float* out = (float*)d_out;

  char* ws = (char*)d_ws;
  size_t off = 0;
  auto alloc = [&](size_t bytes){ void* p = ws + off; off += (bytes + 255) & ~(size_t)255; return p; };
  float* no     = (float*)alloc((size_t)NN*4);
  float* ni     = (float*)alloc((size_t)NN*4);
  int*   rowp   = (int*)  alloc((size_t)(NN+1)*4);
  float* t1     = (float*)alloc((size_t)NN*4);
  float* t2     = (float*)alloc((size_t)NN*4);
  float* b1c    = (float*)alloc((size_t)D*4);
  float* b2c    = (float*)alloc((size_t)D*4);
  float* sW1c   = (float*)alloc((size_t)D*4);
  float* sW2c   = (float*)alloc((size_t)D*4);
  float* sbc    = (float*)alloc(2*4);
  u16*   W1Th   = (u16*)  alloc((size_t)D*D*2);
  u16*   W1Tl   = (u16*)  alloc((size_t)D*D*2);
  u16*   W2Th   = (u16*)  alloc((size_t)D*D*2);
  u16*   W2Tl   = (u16*)  alloc((size_t)D*D*2);
  int*   csr    = (int*)  alloc((size_t)EDGES*4);
  u16*   Hh     = (u16*)  alloc((size_t)NN*D*2);
  u16*   Hl     = (u16*)  alloc((size_t)NN*D*2);
  float* Y      = (float*)alloc((size_t)NN*D*4);
  u16*   Xh     = (u16*)  alloc((size_t)NN*D*2);
  u16*   Xl     = (u16*)  alloc((size_t)NN*D*2);
  // bf16 h2 (Hb) reuses Hh's buffer in agg mode 1 (Hh's split role is dead by then)
  u16*   Hb     = Hh;

  graphprep_kernel<<<NB, 512, 0, stream>>>(src, dst, no, ni, rowp, csr);
  bcvt_kernel     <<<1, 512, 0, stream>>>((const u16*)x, b1, b2, sW1, sW2, sb1, sb2,
                                          b1c, b2c, sW1c, sW2c, sbc);
  tsplit_kernel   <<<dim3(16,16,2), dim3(32,8), 0, stream>>>((const u16*)x, W1, W2,
                                          W1Th, W1Tl, W2Th, W2Tl);
  xsplit_kernel   <<<2048, 256, 0, stream>>>(x, Xh, Xl);

  // conv1: Y = (x @ W1) * no ; h1 = relu(agg) -> split bf16 (Hh, Hl)
  gemm256<<<256, 512, 0, stream>>>(Xh, Xl, W1Th, W1Tl, Y, no);
  agg_kernel<<<NN/2, 256, 0, stream>>>(Y, rowp, csr, ni, b1c, Hh, Hl,
                                       nullptr, nullptr, nullptr, nullptr, 0);
  // conv2: Y = (h1 @ W2) * no ; h2 = relu(agg) -> bf16 Hb + fused score dots
  gemm256<<<256, 512, 0, stream>>>(Hh, Hl, W2Th, W2Tl, Y, no);
  agg_kernel<<<NN/2, 256, 0, stream>>>(Y, rowp, csr, ni, b2c, Hb, nullptr,
                                       sW1c, sW2c, t1, t2, 1);

  scoretopk_readout_kernel<<<NB, 512, 0, stream>>>(t1, t2, rowp, csr, no, ni, sbc,
                                       Hb, out, out + (size_t)NB*KEEP*D);
}

// Round 13
// 312.208 us; speedup vs baseline: 1.5201x; 1.0021x over previous
//
#include <hip/hip_runtime.h>
#include <math.h>

typedef unsigned short u16;
typedef __attribute__((ext_vector_type(8))) short bf16x8;
typedef __attribute__((ext_vector_type(4))) float f32x4;

#define NN 32768      // total nodes
#define EDGES 524288  // total edges
#define NB 64         // graphs
#define NPG 512       // nodes per graph
#define EPG 8192      // edges per graph (contiguous in src/dst)
#define KEEP 256      // kept per graph
#define D 512         // feature dim

__device__ __forceinline__ float b2f(u16 h){ return __uint_as_float(((unsigned)h)<<16); }
__device__ __forceinline__ u16 f2b(float f){
  unsigned u = __float_as_uint(f);
  unsigned r = u + 0x7FFFu + ((u>>16)&1u);   // RNE
  return (u16)(r>>16);
}

// async global->LDS, 16B per lane (dest must be wave-uniform base + lane*16)
__device__ __forceinline__ void gload16(const void* g, void* l){
  __builtin_amdgcn_global_load_lds((const __attribute__((address_space(1))) void*)g,
                                   (__attribute__((address_space(3))) void*)l, 16, 0, 0);
}

// ---- inline dtype flag: 1 if x is f32, 0 if bf16 (sample first 128 u16s) ----
// f32 buffers read as u16 expose random mantissa halves -> ~45% have exp>140;
// bf16 N(0,1) data never does. Wave 0 reduces, LDS-broadcasts to the block.
__device__ __forceinline__ int flag_f32(const u16* __restrict__ xb, int tid){
  __shared__ int fl;
  if (tid < 64){
    u16 v0 = xb[tid*2], v1 = xb[tid*2+1];
    int c = ((((v0>>7)&0xFF) > 140) ? 1 : 0) + ((((v1>>7)&0xFF) > 140) ? 1 : 0);
    #pragma unroll
    for (int o=32; o>=1; o>>=1) c += __shfl_xor(c, o);
    if (tid == 0) fl = (c > 8) ? 1 : 0;
  }
  __syncthreads();
  return fl;
}

// ---------- fused per-graph preprocessing: degrees, norms, rowp, CSR fill ----------
__global__ __launch_bounds__(512) void graphprep_kernel(
    const int* __restrict__ src, const int* __restrict__ dst,
    float* __restrict__ no, float* __restrict__ ni,
    int* __restrict__ rowp, int* __restrict__ csr)
{
  __shared__ int dego[NPG], degi[NPG], s[NPG], start[NPG], cur[NPG];
  int g = blockIdx.x, n = threadIdx.x;
  dego[n] = 0; degi[n] = 0; cur[n] = 0;
  __syncthreads();
  int ebase = g*EPG;
  #pragma unroll
  for (int i = 0; i < 16; i++){
    int e = ebase + n + i*512;
    atomicAdd(&dego[src[e] & (NPG-1)], 1);
    atomicAdd(&degi[dst[e] & (NPG-1)], 1);
  }
  __syncthreads();
  int di = degi[n];
  s[n] = di;
  __syncthreads();
  for (int off=1; off<NPG; off<<=1){
    int val = (n>=off) ? s[n-off] : 0;
    __syncthreads();
    s[n] += val;
    __syncthreads();
  }
  int excl = s[n] - di;
  start[n] = excl;
  int a = dego[n]; if (a<1) a=1;
  int b = di;      if (b<1) b=1;
  int v = g*NPG + n;
  no[v] = (float)(1.0/sqrt((double)a));
  ni[v] = (float)(1.0/sqrt((double)b));
  rowp[v] = ebase + excl;
  if (g == NB-1 && n == NPG-1) rowp[NN] = EDGES;
  __syncthreads();
  #pragma unroll
  for (int i = 0; i < 16; i++){
    int e = ebase + n + i*512;
    int dl = dst[e] & (NPG-1);
    int pos = atomicAdd(&cur[dl], 1);
    csr[ebase + start[dl] + pos] = src[e];
  }
}

// ---------- small-tensor conversion to canonical f32 ----------
__global__ __launch_bounds__(512) void bcvt_kernel(const u16* __restrict__ xb,
    const void* b1, const void* b2, const void* sW1, const void* sW2,
    const void* sb1, const void* sb2,
    float* b1c, float* b2c, float* sW1c, float* sW2c, float* sbc)
{
  int t = threadIdx.x;
  int f = flag_f32(xb, t);
  #define CV(p,i) (f ? ((const float*)(p))[i] : b2f(((const u16*)(p))[i]))
  b1c[t]  = CV(b1, t);
  b2c[t]  = CV(b2, t);
  sW1c[t] = CV(sW1, t);
  sW2c[t] = CV(sW2, t);
  if (t==0){ sbc[0] = CV(sb1,0); sbc[1] = CV(sb2,0); }
  #undef CV
}

// ---------- weight transpose + hi/lo bf16 split; z selects W1/W2 ----------
__global__ void tsplit_kernel(const u16* __restrict__ xb,
                              const void* __restrict__ W1, const void* __restrict__ W2,
                              u16* __restrict__ W1Th, u16* __restrict__ W1Tl,
                              u16* __restrict__ W2Th, u16* __restrict__ W2Tl){
  __shared__ float tile[32][33];
  int tid = threadIdx.x + threadIdx.y*32;
  int f = flag_f32(xb, tid);
  const void* W = blockIdx.z ? W2 : W1;
  u16* WTh = blockIdx.z ? W2Th : W1Th;
  u16* WTl = blockIdx.z ? W2Tl : W1Tl;
  int bx = blockIdx.x*32, by = blockIdx.y*32;
  int tx = threadIdx.x, ty = threadIdx.y; // (32,8)
  #pragma unroll
  for (int i=0;i<4;i++){
    size_t idx = (size_t)(by+ty+i*8)*D + bx+tx;
    tile[ty+i*8][tx] = f ? ((const float*)W)[idx] : b2f(((const u16*)W)[idx]);
  }
  __syncthreads();
  #pragma unroll
  for (int i=0;i<4;i++){
    float v = tile[tx][ty+i*8];
    u16 h = f2b(v);
    size_t o = (size_t)(bx+ty+i*8)*D + by+tx;
    WTh[o] = h;
    WTl[o] = f2b(v - b2f(h));
  }
}

// ---------- x split: f32 (or bf16) -> bf16 hi/lo (grid-stride) ----------
__global__ __launch_bounds__(256) void xsplit_kernel(const void* __restrict__ X,
    u16* __restrict__ Xh, u16* __restrict__ Xl)
{
  int f = flag_f32((const u16*)X, threadIdx.x);
  size_t stride = (size_t)gridDim.x*256*4;
  for (size_t i = ((size_t)blockIdx.x*256 + threadIdx.x)*4; i < (size_t)NN*D; i += stride){
    float v0,v1,v2,v3;
    if (f){
      float4 fv = *(const float4*)((const float*)X + i);
      v0=fv.x; v1=fv.y; v2=fv.z; v3=fv.w;
    } else {
      ushort4 uv = *(const ushort4*)((const u16*)X + i);
      v0=b2f(uv.x); v1=b2f(uv.y); v2=b2f(uv.z); v3=b2f(uv.w);
    }
    ushort4 hh, hl;
    hh.x=f2b(v0); hl.x=f2b(v0-b2f(hh.x));
    hh.y=f2b(v1); hl.y=f2b(v1-b2f(hh.y));
    hh.z=f2b(v2); hl.z=f2b(v2-b2f(hh.z));
    hh.w=f2b(v3); hl.w=f2b(v3-b2f(hh.w));
    *(ushort4*)(Xh+i) = hh;
    *(ushort4*)(Xl+i) = hl;
  }
}

// ---------------- GEMM: C = (A @ W) * rowscale; A,B pre-split bf16 hi/lo ----------------
// 256x256 tile, 8 waves (2M x 4N), BK=32, double-buffered LDS (128 KB),
// STAGE(next) -> ds_read(cur) -> MFMA -> vmcnt(0) -> barrier (R7/R9/R11 known-good).

__device__ __forceinline__ void gemm_tile256(int id, int& brow, int& bcol){
  int xcd = id & 7, k = id >> 3;           // k: 0..31
  brow = (xcd + 8*(k >> 1)) * 256;         // both bcol-blocks of a panel -> same XCD
  bcol = (k & 1) * 256;
}

__global__ __launch_bounds__(512, 2) void gemm256(
    const u16* __restrict__ Ahg, const u16* __restrict__ Alg,
    const u16* __restrict__ BTh, const u16* __restrict__ BTl,
    float* __restrict__ C, const float* __restrict__ rowscale)
{
  __shared__ alignas(16) u16 lds[2][4][8192];
  int t = threadIdx.x;
  int brow, bcol;
  gemm_tile256(blockIdx.x, brow, bcol);
  int wid = t>>6, lane = t&63;
  int wr = wid>>2, wc = wid&3;             // wave grid 2 x 4, wave owns 128x64
  int q = lane>>4, r = lane&15;
  f32x4 acc[8][4] = {};

  int c0 = wid*128 + lane, c1 = c0 + 64;
  int q0 = c0>>8, r0 = c0&255, q1 = c1>>8, r1 = c1&255;
  const u16* sA0h = Ahg + (size_t)(brow+r0)*D + q0*8;
  const u16* sA1h = Ahg + (size_t)(brow+r1)*D + q1*8;
  const u16* sA0l = Alg + (size_t)(brow+r0)*D + q0*8;
  const u16* sA1l = Alg + (size_t)(brow+r1)*D + q1*8;
  const u16* sB0h = BTh + (size_t)(bcol+r0)*D + q0*8;
  const u16* sB1h = BTh + (size_t)(bcol+r1)*D + q1*8;
  const u16* sB0l = BTl + (size_t)(bcol+r0)*D + q0*8;
  const u16* sB1l = BTl + (size_t)(bcol+r1)*D + q1*8;

  #define STAGEK(B, KT) { int ko = (KT)*32; \
    gload16(sA0h+ko, &lds[B][0][c0*8]); gload16(sA1h+ko, &lds[B][0][c1*8]); \
    gload16(sA0l+ko, &lds[B][1][c0*8]); gload16(sA1l+ko, &lds[B][1][c1*8]); \
    gload16(sB0h+ko, &lds[B][2][c0*8]); gload16(sB1h+ko, &lds[B][2][c1*8]); \
    gload16(sB0l+ko, &lds[B][3][c0*8]); gload16(sB1l+ko, &lds[B][3][c1*8]); }

  STAGEK(0, 0)
  asm volatile("s_waitcnt vmcnt(0)" ::: "memory");
  __syncthreads();
  int cur = 0;
  for (int kt=0; kt<16; kt++){
    if (kt < 15) STAGEK(cur^1, kt+1)
    bf16x8 fbh[4], fbl[4];
    #pragma unroll
    for (int n=0;n<4;n++){
      fbh[n] = *(const bf16x8*)(&lds[cur][2][(q*256 + wc*64 + n*16 + r)*8]);
      fbl[n] = *(const bf16x8*)(&lds[cur][3][(q*256 + wc*64 + n*16 + r)*8]);
    }
    __builtin_amdgcn_s_setprio(1);
    #pragma unroll
    for (int m=0;m<8;m++){
      bf16x8 fah = *(const bf16x8*)(&lds[cur][0][(q*256 + wr*128 + m*16 + r)*8]);
      bf16x8 fal = *(const bf16x8*)(&lds[cur][1][(q*256 + wr*128 + m*16 + r)*8]);
      #pragma unroll
      for (int n=0;n<4;n++){
        acc[m][n] = __builtin_amdgcn_mfma_f32_16x16x32_bf16(fah, fbh[n], acc[m][n], 0,0,0);
        acc[m][n] = __builtin_amdgcn_mfma_f32_16x16x32_bf16(fah, fbl[n], acc[m][n], 0,0,0);
        acc[m][n] = __builtin_amdgcn_mfma_f32_16x16x32_bf16(fal, fbh[n], acc[m][n], 0,0,0);
      }
    }
    __builtin_amdgcn_s_setprio(0);
    asm volatile("s_waitcnt vmcnt(0)" ::: "memory");
    __syncthreads();
    cur ^= 1;
  }
  #undef STAGEK

  #pragma unroll
  for (int m=0;m<8;m++){
    int rowb = brow + wr*128 + m*16 + q*4;
    #pragma unroll
    for (int n=0;n<4;n++){
      int col = bcol + wc*64 + n*16 + r;
      #pragma unroll
      for (int g=0; g<4; g++){
        int row = rowb + g;
        C[(size_t)row*D + col] = acc[m][n][g] * rowscale[row];
      }
    }
  }
}

// -------- edge aggregation: relu( (sum_{u in N(v)} Y[u]) * ni[v] + b ) --------
// mode 0: write split bf16 hi/lo (Hh, Hl) for conv2's A.
// mode 1: write bf16 H (Hb) + fused f32 score dots (t1,t2 from PRE-rounding value).

__global__ __launch_bounds__(256) void agg_kernel(
    const float* __restrict__ Y, const int* __restrict__ rowp,
    const int* __restrict__ csr, const float* __restrict__ ni,
    const float* __restrict__ bias,
    u16* __restrict__ Hh, u16* __restrict__ Hl,
    const float* __restrict__ sW1, const float* __restrict__ sW2,
    float* __restrict__ t1, float* __restrict__ t2, int mode)
{
  int i = blockIdx.x;
  int xcd = i & 7, j = i >> 3;              // j: 0..2047
  int half = threadIdx.x >> 7;              // node within pair
  int t = threadIdx.x & 127;                // float4 chunk
  int lane = threadIdx.x & 63;
  int v = (xcd + 8*(j >> 8))*NPG + ((j & 255)*2 + half);
  int rp0 = rowp[v], rp1 = rowp[v+1];
  const float4* Yv = (const float4*)Y;
  float4 a = {0.f,0.f,0.f,0.f};
  for (int eb = rp0; eb < rp1; eb += 64){
    int cnt = rp1 - eb; if (cnt > 64) cnt = 64;
    int idx = (lane < cnt) ? csr[eb + lane] : 0;
    int e = 0;
    for (; e+8 <= cnt; e += 8){
      int u0 = __shfl(idx, e),   u1 = __shfl(idx, e+1);
      int u2 = __shfl(idx, e+2), u3 = __shfl(idx, e+3);
      int u4 = __shfl(idx, e+4), u5 = __shfl(idx, e+5);
      int u6 = __shfl(idx, e+6), u7 = __shfl(idx, e+7);
      float4 y0 = Yv[(size_t)u0*128 + t];
      float4 y1 = Yv[(size_t)u1*128 + t];
      float4 y2 = Yv[(size_t)u2*128 + t];
      float4 y3 = Yv[(size_t)u3*128 + t];
      float4 y4 = Yv[(size_t)u4*128 + t];
      float4 y5 = Yv[(size_t)u5*128 + t];
      float4 y6 = Yv[(size_t)u6*128 + t];
      float4 y7 = Yv[(size_t)u7*128 + t];
      a.x += ((y0.x + y1.x) + (y2.x + y3.x)) + ((y4.x + y5.x) + (y6.x + y7.x));
      a.y += ((y0.y + y1.y) + (y2.y + y3.y)) + ((y4.y + y5.y) + (y6.y + y7.y));
      a.z += ((y0.z + y1.z) + (y2.z + y3.z)) + ((y4.z + y5.z) + (y6.z + y7.z));
      a.w += ((y0.w + y1.w) + (y2.w + y3.w)) + ((y4.w + y5.w) + (y6.w + y7.w));
    }
    for (; e+4 <= cnt; e += 4){
      int u0 = __shfl(idx, e),   u1 = __shfl(idx, e+1);
      int u2 = __shfl(idx, e+2), u3 = __shfl(idx, e+3);
      float4 y0 = Yv[(size_t)u0*128 + t];
      float4 y1 = Yv[(size_t)u1*128 + t];
      float4 y2 = Yv[(size_t)u2*128 + t];
      float4 y3 = Yv[(size_t)u3*128 + t];
      a.x += (y0.x + y1.x) + (y2.x + y3.x);
      a.y += (y0.y + y1.y) + (y2.y + y3.y);
      a.z += (y0.z + y1.z) + (y2.z + y3.z);
      a.w += (y0.w + y1.w) + (y2.w + y3.w);
    }
    for (; e < cnt; e++){
      int u = __shfl(idx, e);
      float4 y = Yv[(size_t)u*128 + t];
      a.x += y.x; a.y += y.y; a.z += y.z; a.w += y.w;
    }
  }
  float w = ni[v];
  float4 b4 = ((const float4*)bias)[t];
  float4 rr;
  rr.x = fmaxf(a.x*w + b4.x, 0.f);
  rr.y = fmaxf(a.y*w + b4.y, 0.f);
  rr.z = fmaxf(a.z*w + b4.z, 0.f);
  rr.w = fmaxf(a.w*w + b4.w, 0.f);

  if (mode == 0){
    ushort4 hh, hl;
    hh.x = f2b(rr.x); hl.x = f2b(rr.x - b2f(hh.x));
    hh.y = f2b(rr.y); hl.y = f2b(rr.y - b2f(hh.y));
    hh.z = f2b(rr.z); hl.z = f2b(rr.z - b2f(hh.z));
    hh.w = f2b(rr.w); hl.w = f2b(rr.w - b2f(hh.w));
    *(ushort4*)(Hh + (size_t)v*D + t*4) = hh;
    *(ushort4*)(Hl + (size_t)v*D + t*4) = hl;
  } else {
    ushort4 hb;
    hb.x = f2b(rr.x); hb.y = f2b(rr.y); hb.z = f2b(rr.z); hb.w = f2b(rr.w);
    *(ushort4*)(Hh + (size_t)v*D + t*4) = hb;   // Hh doubles as bf16 H here
    float4 w1 = ((const float4*)sW1)[t];
    float4 w2 = ((const float4*)sW2)[t];
    float p1 = rr.x*w1.x + rr.y*w1.y + rr.z*w1.z + rr.w*w1.w;
    float p2 = rr.x*w2.x + rr.y*w2.y + rr.z*w2.z + rr.w*w2.w;
    #pragma unroll
    for (int off=32; off>=1; off>>=1){
      p1 += __shfl_xor(p1, off);
      p2 += __shfl_xor(p2, off);
    }
    __shared__ float red1[4], red2[4];
    int wv = threadIdx.x>>6;
    if (lane==0){ red1[wv] = p1; red2[wv] = p2; }
    __syncthreads();
    if (t==0){
      t1[v] = red1[half*2] + red1[half*2+1];
      t2[v] = red2[half*2] + red2[half*2+1];
    }
  }
}

// -------- fused score agg + stable top-K + gated gather + readout (per graph) --------

__global__ __launch_bounds__(512) void scoretopk_readout_kernel(
    const float* __restrict__ t1, const float* __restrict__ t2,
    const int* __restrict__ rowp, const int* __restrict__ csr,
    const float* __restrict__ no, const float* __restrict__ ni,
    const float* __restrict__ sbc, const u16* __restrict__ Hb,
    float* __restrict__ outp, float* __restrict__ outg)
{
  __shared__ unsigned long long key[NPG];
  __shared__ float scl[NPG];
  __shared__ int sp[KEEP];
  __shared__ float sg[KEEP];
  __shared__ float4 redmx[3*128], redsm[3*128];
  int g = blockIdx.x, n = threadIdx.x;
  int v = g*NPG + n;
  // scores (f64, matches np ordering)
  double a1 = 0.0, a2 = 0.0;
  int rp1 = rowp[v+1];
  for (int e=rowp[v]; e<rp1; e++){
    int u = csr[e];
    double w = (double)no[u];
    a1 += (double)t1[u]*w;
    a2 += (double)t2[u]*w;
  }
  double wi = (double)ni[v];
  double s1 = a1*wi + (double)sbc[0];
  double s2 = a2*wi + (double)sbc[1];
  float s = (float)(0.5*(s1+s2));
  scl[n] = s;
  unsigned u = __float_as_uint(s);
  u = (u & 0x80000000u) ? ~u : (u | 0x80000000u);  // order-preserving (ascending)
  unsigned kd = ~u;                                 // descending score
  key[n] = ((unsigned long long)kd<<32) | (unsigned)n;
  __syncthreads();
  for (int k=2; k<=NPG; k<<=1){
    for (int j=k>>1; j>0; j>>=1){
      int ixj = n ^ j;
      if (ixj > n){
        unsigned long long a = key[n], b = key[ixj];
        bool up = ((n & k) == 0);
        if ((a > b) == up){ key[n] = b; key[ixj] = a; }
      }
      __syncthreads();
    }
  }
  if (n < KEEP){
    int idx = (int)(key[n] & 0xFFFFFFFFull);
    sp[n] = g*NPG + idx;
    sg[n] = tanhf(scl[idx]);
  }
  __syncthreads();
  // readout: quarter q handles ranks q, q+4, ...; c = float4 chunk
  int quarter = n >> 7, c = n & 127;
  float4 mx = {-INFINITY,-INFINITY,-INFINITY,-INFINITY};
  float4 sm = {0.f,0.f,0.f,0.f};
  for (int rI = quarter; rI < KEEP; rI += 4){
    int node = sp[rI];
    float gt = sg[rI];
    ushort4 hv = *(const ushort4*)(Hb + (size_t)node*D + c*4);
    float4 vv;
    vv.x = b2f(hv.x)*gt; vv.y = b2f(hv.y)*gt;
    vv.z = b2f(hv.z)*gt; vv.w = b2f(hv.w)*gt;
    ((float4*)(outp + (size_t)(g*KEEP + rI)*D))[c] = vv;
    mx.x = fmaxf(mx.x, vv.x); mx.y = fmaxf(mx.y, vv.y);
    mx.z = fmaxf(mx.z, vv.z); mx.w = fmaxf(mx.w, vv.w);
    sm.x += vv.x; sm.y += vv.y; sm.z += vv.z; sm.w += vv.w;
  }
  if (quarter > 0){ redmx[(quarter-1)*128 + c] = mx; redsm[(quarter-1)*128 + c] = sm; }
  __syncthreads();
  if (quarter == 0){
    #pragma unroll
    for (int qq=0; qq<3; qq++){
      float4 omx = redmx[qq*128 + c], osm = redsm[qq*128 + c];
      mx.x = fmaxf(mx.x, omx.x); mx.y = fmaxf(mx.y, omx.y);
      mx.z = fmaxf(mx.z, omx.z); mx.w = fmaxf(mx.w, omx.w);
      sm.x += osm.x; sm.y += osm.y; sm.z += osm.z; sm.w += osm.w;
    }
    ((float4*)(outg + (size_t)g*1024))[c] = mx;
    ((float4*)(outg + (size_t)g*1024 + 512))[c] = sm;
  }
}

// ---------------- launch ----------------

extern "C" void kernel_launch(void* const* d_in, const int* in_sizes, int n_in,
                              void* d_out, int out_size, void* d_ws, size_t ws_size,
                              hipStream_t stream)
{
  (void)in_sizes; (void)n_in; (void)out_size; (void)ws_size;
  const void* x   = d_in[0];
  const int* src  = (const int*)d_in[1];
  const int* dst  = (const int*)d_in[2];
  const void* W1  = d_in[3];
  const void* b1  = d_in[4];
  const void* W2  = d_in[5];
  const void* b2  = d_in[6];
  const void* sW1 = d_in[7];
  const void* sb1 = d_in[8];
  const void* sW2 = d_in[9];
  const void* sb2 = d_in[10];
  float* out = (float*)d_out;

  char* ws = (char*)d_ws;
  size_t off = 0;
  auto alloc = [&](size_t bytes){ void* p = ws + off; off += (bytes + 255) & ~(size_t)255; return p; };
  float* no     = (float*)alloc((size_t)NN*4);
  float* ni     = (float*)alloc((size_t)NN*4);
  int*   rowp   = (int*)  alloc((size_t)(NN+1)*4);
  float* t1     = (float*)alloc((size_t)NN*4);
  float* t2     = (float*)alloc((size_t)NN*4);
  float* b1c    = (float*)alloc((size_t)D*4);
  float* b2c    = (float*)alloc((size_t)D*4);
  float* sW1c   = (float*)alloc((size_t)D*4);
  float* sW2c   = (float*)alloc((size_t)D*4);
  float* sbc    = (float*)alloc(2*4);
  u16*   W1Th   = (u16*)  alloc((size_t)D*D*2);
  u16*   W1Tl   = (u16*)  alloc((size_t)D*D*2);
  u16*   W2Th   = (u16*)  alloc((size_t)D*D*2);
  u16*   W2Tl   = (u16*)  alloc((size_t)D*D*2);
  int*   csr    = (int*)  alloc((size_t)EDGES*4);
  u16*   Hh     = (u16*)  alloc((size_t)NN*D*2);
  u16*   Hl     = (u16*)  alloc((size_t)NN*D*2);
  float* Y      = (float*)alloc((size_t)NN*D*4);
  u16*   Xh     = (u16*)  alloc((size_t)NN*D*2);
  u16*   Xl     = (u16*)  alloc((size_t)NN*D*2);
  // bf16 h2 (Hb) reuses Hh's buffer in agg mode 1 (Hh's split role is dead by then)
  u16*   Hb     = Hh;

  graphprep_kernel<<<NB, 512, 0, stream>>>(src, dst, no, ni, rowp, csr);
  bcvt_kernel     <<<1, 512, 0, stream>>>((const u16*)x, b1, b2, sW1, sW2, sb1, sb2,
                                          b1c, b2c, sW1c, sW2c, sbc);
  tsplit_kernel   <<<dim3(16,16,2), dim3(32,8), 0, stream>>>((const u16*)x, W1, W2,
                                          W1Th, W1Tl, W2Th, W2Tl);
  xsplit_kernel   <<<2048, 256, 0, stream>>>(x, Xh, Xl);

  // conv1: Y = (x @ W1) * no ; h1 = relu(agg) -> split bf16 (Hh, Hl)
  gemm256<<<256, 512, 0, stream>>>(Xh, Xl, W1Th, W1Tl, Y, no);
  agg_kernel<<<NN/2, 256, 0, stream>>>(Y, rowp, csr, ni, b1c, Hh, Hl,
                                       nullptr, nullptr, nullptr, nullptr, 0);
  // conv2: Y = (h1 @ W2) * no ; h2 = relu(agg) -> bf16 Hb + fused score dots
  gemm256<<<256, 512, 0, stream>>>(Hh, Hl, W2Th, W2Tl, Y, no);
  agg_kernel<<<NN/2, 256, 0, stream>>>(Y, rowp, csr, ni, b2c, Hb, nullptr,
                                       sW1c, sW2c, t1, t2, 1);

  scoretopk_readout_kernel<<<NB, 512, 0, stream>>>(t1, t2, rowp, csr, no, ni, sbc,
                                       Hb, out, out + (size_t)NB*KEEP*D);
}

// Round 14
// 284.402 us; speedup vs baseline: 1.6687x; 1.0978x over previous
//
#include <hip/hip_runtime.h>
#include <math.h>

typedef unsigned short u16;
typedef __attribute__((ext_vector_type(8))) short bf16x8;
typedef __attribute__((ext_vector_type(4))) float f32x4;

#define NN 32768      // total nodes
#define EDGES 524288  // total edges
#define NB 64         // graphs
#define NPG 512       // nodes per graph
#define EPG 8192      // edges per graph (contiguous in src/dst)
#define KEEP 256      // kept per graph
#define D 512         // feature dim

__device__ __forceinline__ float b2f(u16 h){ return __uint_as_float(((unsigned)h)<<16); }
__device__ __forceinline__ u16 f2b(float f){
  unsigned u = __float_as_uint(f);
  unsigned r = u + 0x7FFFu + ((u>>16)&1u);   // RNE
  return (u16)(r>>16);
}

// async global->LDS, 16B per lane (dest must be wave-uniform base + lane*16)
__device__ __forceinline__ void gload16(const void* g, void* l){
  __builtin_amdgcn_global_load_lds((const __attribute__((address_space(1))) void*)g,
                                   (__attribute__((address_space(3))) void*)l, 16, 0, 0);
}

// ---- inline dtype flag: 1 if x is f32, 0 if bf16 (sample first 128 u16s) ----
__device__ __forceinline__ int flag_f32(const u16* __restrict__ xb, int tid){
  __shared__ int fl;
  if (tid < 64){
    u16 v0 = xb[tid*2], v1 = xb[tid*2+1];
    int c = ((((v0>>7)&0xFF) > 140) ? 1 : 0) + ((((v1>>7)&0xFF) > 140) ? 1 : 0);
    #pragma unroll
    for (int o=32; o>=1; o>>=1) c += __shfl_xor(c, o);
    if (tid == 0) fl = (c > 8) ? 1 : 0;
  }
  __syncthreads();
  return fl;
}

// ---------- fused preprocessing (grid-partitioned, 512 threads/block) ----------
// blocks [0,64):   per-graph degrees/norms/rowp/CSR
// block  64:       small-tensor conversion to f32
// blocks [65,577): weight transpose+split (512 tiles: id = b-65, z=id>>8)
// blocks [577,2048): x split, grid-stride
__global__ __launch_bounds__(512) void prep_kernel(
    const int* __restrict__ src, const int* __restrict__ dst,
    float* __restrict__ no, float* __restrict__ ni,
    int* __restrict__ rowp, int* __restrict__ csr,
    const void* __restrict__ x,
    const void* b1, const void* b2, const void* sW1v, const void* sW2v,
    const void* sb1, const void* sb2,
    float* b1c, float* b2c, float* sW1c, float* sW2c, float* sbc,
    const void* __restrict__ W1, const void* __restrict__ W2,
    u16* __restrict__ W1Th, u16* __restrict__ W1Tl,
    u16* __restrict__ W2Th, u16* __restrict__ W2Tl,
    u16* __restrict__ Xh, u16* __restrict__ Xl)
{
  __shared__ int sh_i[5][NPG];         // graphprep: dego, degi, s, start, cur
  __shared__ float tile[32][33];       // tsplit
  int b = blockIdx.x, t = threadIdx.x;

  if (b < NB){
    // ---- graphprep ----
    int* dego = sh_i[0]; int* degi = sh_i[1]; int* s = sh_i[2];
    int* start = sh_i[3]; int* cur = sh_i[4];
    int g = b, n = t;
    dego[n] = 0; degi[n] = 0; cur[n] = 0;
    __syncthreads();
    int ebase = g*EPG;
    #pragma unroll
    for (int i = 0; i < 16; i++){
      int e = ebase + n + i*512;
      atomicAdd(&dego[src[e] & (NPG-1)], 1);
      atomicAdd(&degi[dst[e] & (NPG-1)], 1);
    }
    __syncthreads();
    int di = degi[n];
    s[n] = di;
    __syncthreads();
    for (int off=1; off<NPG; off<<=1){
      int val = (n>=off) ? s[n-off] : 0;
      __syncthreads();
      s[n] += val;
      __syncthreads();
    }
    int excl = s[n] - di;
    start[n] = excl;
    int a = dego[n]; if (a<1) a=1;
    int bb = di;     if (bb<1) bb=1;
    int v = g*NPG + n;
    no[v] = (float)(1.0/sqrt((double)a));
    ni[v] = (float)(1.0/sqrt((double)bb));
    rowp[v] = ebase + excl;
    if (g == NB-1 && n == NPG-1) rowp[NN] = EDGES;
    __syncthreads();
    #pragma unroll
    for (int i = 0; i < 16; i++){
      int e = ebase + n + i*512;
      int dl = dst[e] & (NPG-1);
      int pos = atomicAdd(&cur[dl], 1);
      csr[ebase + start[dl] + pos] = src[e];
    }
  } else if (b == NB){
    // ---- bcvt ----
    int f = flag_f32((const u16*)x, t);
    #define CV(p,i) (f ? ((const float*)(p))[i] : b2f(((const u16*)(p))[i]))
    b1c[t]  = CV(b1, t);
    b2c[t]  = CV(b2, t);
    sW1c[t] = CV(sW1v, t);
    sW2c[t] = CV(sW2v, t);
    if (t==0){ sbc[0] = CV(sb1,0); sbc[1] = CV(sb2,0); }
    #undef CV
  } else if (b < NB + 1 + 512){
    // ---- tsplit ----
    int f = flag_f32((const u16*)x, t);
    int id = b - (NB+1);
    const void* W = (id >> 8) ? W2 : W1;
    u16* WTh = (id >> 8) ? W2Th : W1Th;
    u16* WTl = (id >> 8) ? W2Tl : W1Tl;
    int rem = id & 255;
    int bx = (rem & 15)*32, by = (rem >> 4)*32;
    int tx = t & 31, ty = t >> 5;   // ty 0..15
    #pragma unroll
    for (int i=0;i<2;i++){
      size_t idx = (size_t)(by+ty+i*16)*D + bx+tx;
      tile[ty+i*16][tx] = f ? ((const float*)W)[idx] : b2f(((const u16*)W)[idx]);
    }
    __syncthreads();
    #pragma unroll
    for (int i=0;i<2;i++){
      float v = tile[tx][ty+i*16];
      u16 h = f2b(v);
      size_t o = (size_t)(bx+ty+i*16)*D + by+tx;
      WTh[o] = h;
      WTl[o] = f2b(v - b2f(h));
    }
  } else {
    // ---- xsplit (grid-stride) ----
    int f = flag_f32((const u16*)x, t);
    int nblk = gridDim.x - (NB+1+512);
    int bid  = b - (NB+1+512);
    size_t stride = (size_t)nblk*512*4;
    for (size_t i = ((size_t)bid*512 + t)*4; i < (size_t)NN*D; i += stride){
      float v0,v1,v2,v3;
      if (f){
        float4 fv = *(const float4*)((const float*)x + i);
        v0=fv.x; v1=fv.y; v2=fv.z; v3=fv.w;
      } else {
        ushort4 uv = *(const ushort4*)((const u16*)x + i);
        v0=b2f(uv.x); v1=b2f(uv.y); v2=b2f(uv.z); v3=b2f(uv.w);
      }
      ushort4 hh, hl;
      hh.x=f2b(v0); hl.x=f2b(v0-b2f(hh.x));
      hh.y=f2b(v1); hl.y=f2b(v1-b2f(hh.y));
      hh.z=f2b(v2); hl.z=f2b(v2-b2f(hh.z));
      hh.w=f2b(v3); hl.w=f2b(v3-b2f(hh.w));
      *(ushort4*)(Xh+i) = hh;
      *(ushort4*)(Xl+i) = hl;
    }
  }
}

// ---------------- GEMM: C = (A @ W) * rowscale; A,B pre-split bf16 hi/lo ----------------
// 256x256 tile, 8 waves (2M x 4N), BK=32, double-buffered LDS (128 KB),
// STAGE(next) -> ds_read(cur) -> MFMA -> vmcnt(0) -> barrier (known-good, ~790 TF).

__device__ __forceinline__ void gemm_tile256(int id, int& brow, int& bcol){
  int xcd = id & 7, k = id >> 3;           // k: 0..31
  brow = (xcd + 8*(k >> 1)) * 256;         // both bcol-blocks of a panel -> same XCD
  bcol = (k & 1) * 256;
}

__global__ __launch_bounds__(512, 2) void gemm256(
    const u16* __restrict__ Ahg, const u16* __restrict__ Alg,
    const u16* __restrict__ BTh, const u16* __restrict__ BTl,
    float* __restrict__ C, const float* __restrict__ rowscale)
{
  __shared__ alignas(16) u16 lds[2][4][8192];
  int t = threadIdx.x;
  int brow, bcol;
  gemm_tile256(blockIdx.x, brow, bcol);
  int wid = t>>6, lane = t&63;
  int wr = wid>>2, wc = wid&3;             // wave grid 2 x 4, wave owns 128x64
  int q = lane>>4, r = lane&15;
  f32x4 acc[8][4] = {};

  int c0 = wid*128 + lane, c1 = c0 + 64;
  int q0 = c0>>8, r0 = c0&255, q1 = c1>>8, r1 = c1&255;
  const u16* sA0h = Ahg + (size_t)(brow+r0)*D + q0*8;
  const u16* sA1h = Ahg + (size_t)(brow+r1)*D + q1*8;
  const u16* sA0l = Alg + (size_t)(brow+r0)*D + q0*8;
  const u16* sA1l = Alg + (size_t)(brow+r1)*D + q1*8;
  const u16* sB0h = BTh + (size_t)(bcol+r0)*D + q0*8;
  const u16* sB1h = BTh + (size_t)(bcol+r1)*D + q1*8;
  const u16* sB0l = BTl + (size_t)(bcol+r0)*D + q0*8;
  const u16* sB1l = BTl + (size_t)(bcol+r1)*D + q1*8;

  #define STAGEK(B, KT) { int ko = (KT)*32; \
    gload16(sA0h+ko, &lds[B][0][c0*8]); gload16(sA1h+ko, &lds[B][0][c1*8]); \
    gload16(sA0l+ko, &lds[B][1][c0*8]); gload16(sA1l+ko, &lds[B][1][c1*8]); \
    gload16(sB0h+ko, &lds[B][2][c0*8]); gload16(sB1h+ko, &lds[B][2][c1*8]); \
    gload16(sB0l+ko, &lds[B][3][c0*8]); gload16(sB1l+ko, &lds[B][3][c1*8]); }

  STAGEK(0, 0)
  asm volatile("s_waitcnt vmcnt(0)" ::: "memory");
  __syncthreads();
  int cur = 0;
  for (int kt=0; kt<16; kt++){
    if (kt < 15) STAGEK(cur^1, kt+1)
    bf16x8 fbh[4], fbl[4];
    #pragma unroll
    for (int n=0;n<4;n++){
      fbh[n] = *(const bf16x8*)(&lds[cur][2][(q*256 + wc*64 + n*16 + r)*8]);
      fbl[n] = *(const bf16x8*)(&lds[cur][3][(q*256 + wc*64 + n*16 + r)*8]);
    }
    __builtin_amdgcn_s_setprio(1);
    #pragma unroll
    for (int m=0;m<8;m++){
      bf16x8 fah = *(const bf16x8*)(&lds[cur][0][(q*256 + wr*128 + m*16 + r)*8]);
      bf16x8 fal = *(const bf16x8*)(&lds[cur][1][(q*256 + wr*128 + m*16 + r)*8]);
      #pragma unroll
      for (int n=0;n<4;n++){
        acc[m][n] = __builtin_amdgcn_mfma_f32_16x16x32_bf16(fah, fbh[n], acc[m][n], 0,0,0);
        acc[m][n] = __builtin_amdgcn_mfma_f32_16x16x32_bf16(fah, fbl[n], acc[m][n], 0,0,0);
        acc[m][n] = __builtin_amdgcn_mfma_f32_16x16x32_bf16(fal, fbh[n], acc[m][n], 0,0,0);
      }
    }
    __builtin_amdgcn_s_setprio(0);
    asm volatile("s_waitcnt vmcnt(0)" ::: "memory");
    __syncthreads();
    cur ^= 1;
  }
  #undef STAGEK

  #pragma unroll
  for (int m=0;m<8;m++){
    int rowb = brow + wr*128 + m*16 + q*4;
    #pragma unroll
    for (int n=0;n<4;n++){
      int col = bcol + wc*64 + n*16 + r;
      #pragma unroll
      for (int g=0; g<4; g++){
        int row = rowb + g;
        C[(size_t)row*D + col] = acc[m][n][g] * rowscale[row];
      }
    }
  }
}

// -------- edge aggregation: relu( (sum_{u in N(v)} Y[u]) * ni[v] + b ) --------
// mode 0: write split bf16 hi/lo (Hh, Hl).  mode 1: write bf16 Hb + fused score dots.

__global__ __launch_bounds__(256) void agg_kernel(
    const float* __restrict__ Y, const int* __restrict__ rowp,
    const int* __restrict__ csr, const float* __restrict__ ni,
    const float* __restrict__ bias,
    u16* __restrict__ Hh, u16* __restrict__ Hl,
    const float* __restrict__ sW1, const float* __restrict__ sW2,
    float* __restrict__ t1, float* __restrict__ t2, int mode)
{
  int i = blockIdx.x;
  int xcd = i & 7, j = i >> 3;              // j: 0..2047
  int half = threadIdx.x >> 7;              // node within pair
  int t = threadIdx.x & 127;                // float4 chunk
  int lane = threadIdx.x & 63;
  int v = (xcd + 8*(j >> 8))*NPG + ((j & 255)*2 + half);
  int rp0 = rowp[v], rp1 = rowp[v+1];
  const float4* Yv = (const float4*)Y;
  float4 a = {0.f,0.f,0.f,0.f};
  for (int eb = rp0; eb < rp1; eb += 64){
    int cnt = rp1 - eb; if (cnt > 64) cnt = 64;
    int idx = (lane < cnt) ? csr[eb + lane] : 0;
    int e = 0;
    for (; e+8 <= cnt; e += 8){
      int u0 = __shfl(idx, e),   u1 = __shfl(idx, e+1);
      int u2 = __shfl(idx, e+2), u3 = __shfl(idx, e+3);
      int u4 = __shfl(idx, e+4), u5 = __shfl(idx, e+5);
      int u6 = __shfl(idx, e+6), u7 = __shfl(idx, e+7);
      float4 y0 = Yv[(size_t)u0*128 + t];
      float4 y1 = Yv[(size_t)u1*128 + t];
      float4 y2 = Yv[(size_t)u2*128 + t];
      float4 y3 = Yv[(size_t)u3*128 + t];
      float4 y4 = Yv[(size_t)u4*128 + t];
      float4 y5 = Yv[(size_t)u5*128 + t];
      float4 y6 = Yv[(size_t)u6*128 + t];
      float4 y7 = Yv[(size_t)u7*128 + t];
      a.x += ((y0.x + y1.x) + (y2.x + y3.x)) + ((y4.x + y5.x) + (y6.x + y7.x));
      a.y += ((y0.y + y1.y) + (y2.y + y3.y)) + ((y4.y + y5.y) + (y6.y + y7.y));
      a.z += ((y0.z + y1.z) + (y2.z + y3.z)) + ((y4.z + y5.z) + (y6.z + y7.z));
      a.w += ((y0.w + y1.w) + (y2.w + y3.w)) + ((y4.w + y5.w) + (y6.w + y7.w));
    }
    for (; e+4 <= cnt; e += 4){
      int u0 = __shfl(idx, e),   u1 = __shfl(idx, e+1);
      int u2 = __shfl(idx, e+2), u3 = __shfl(idx, e+3);
      float4 y0 = Yv[(size_t)u0*128 + t];
      float4 y1 = Yv[(size_t)u1*128 + t];
      float4 y2 = Yv[(size_t)u2*128 + t];
      float4 y3 = Yv[(size_t)u3*128 + t];
      a.x += (y0.x + y1.x) + (y2.x + y3.x);
      a.y += (y0.y + y1.y) + (y2.y + y3.y);
      a.z += (y0.z + y1.z) + (y2.z + y3.z);
      a.w += (y0.w + y1.w) + (y2.w + y3.w);
    }
    for (; e < cnt; e++){
      int u = __shfl(idx, e);
      float4 y = Yv[(size_t)u*128 + t];
      a.x += y.x; a.y += y.y; a.z += y.z; a.w += y.w;
    }
  }
  float w = ni[v];
  float4 b4 = ((const float4*)bias)[t];
  float4 rr;
  rr.x = fmaxf(a.x*w + b4.x, 0.f);
  rr.y = fmaxf(a.y*w + b4.y, 0.f);
  rr.z = fmaxf(a.z*w + b4.z, 0.f);
  rr.w = fmaxf(a.w*w + b4.w, 0.f);

  if (mode == 0){
    ushort4 hh, hl;
    hh.x = f2b(rr.x); hl.x = f2b(rr.x - b2f(hh.x));
    hh.y = f2b(rr.y); hl.y = f2b(rr.y - b2f(hh.y));
    hh.z = f2b(rr.z); hl.z = f2b(rr.z - b2f(hh.z));
    hh.w = f2b(rr.w); hl.w = f2b(rr.w - b2f(hh.w));
    *(ushort4*)(Hh + (size_t)v*D + t*4) = hh;
    *(ushort4*)(Hl + (size_t)v*D + t*4) = hl;
  } else {
    ushort4 hb;
    hb.x = f2b(rr.x); hb.y = f2b(rr.y); hb.z = f2b(rr.z); hb.w = f2b(rr.w);
    *(ushort4*)(Hh + (size_t)v*D + t*4) = hb;   // Hh doubles as bf16 H here
    float4 w1 = ((const float4*)sW1)[t];
    float4 w2 = ((const float4*)sW2)[t];
    float p1 = rr.x*w1.x + rr.y*w1.y + rr.z*w1.z + rr.w*w1.w;
    float p2 = rr.x*w2.x + rr.y*w2.y + rr.z*w2.z + rr.w*w2.w;
    #pragma unroll
    for (int off=32; off>=1; off>>=1){
      p1 += __shfl_xor(p1, off);
      p2 += __shfl_xor(p2, off);
    }
    __shared__ float red1[4], red2[4];
    int wv = threadIdx.x>>6;
    if (lane==0){ red1[wv] = p1; red2[wv] = p2; }
    __syncthreads();
    if (t==0){
      t1[v] = red1[half*2] + red1[half*2+1];
      t2[v] = red2[half*2] + red2[half*2+1];
    }
  }
}

// -------- score aggregation + stable top-K (per graph) --------

__global__ __launch_bounds__(512) void scoretopk_kernel(
    const float* __restrict__ t1, const float* __restrict__ t2,
    const int* __restrict__ rowp, const int* __restrict__ csr,
    const float* __restrict__ no, const float* __restrict__ ni,
    const float* __restrict__ sbc,
    int* __restrict__ perm, float* __restrict__ gate)
{
  __shared__ unsigned long long key[NPG];
  __shared__ float scl[NPG];
  int g = blockIdx.x, n = threadIdx.x;
  int v = g*NPG + n;
  double a1 = 0.0, a2 = 0.0;
  int rp1 = rowp[v+1];
  for (int e=rowp[v]; e<rp1; e++){
    int u = csr[e];
    double w = (double)no[u];
    a1 += (double)t1[u]*w;
    a2 += (double)t2[u]*w;
  }
  double wi = (double)ni[v];
  double s1 = a1*wi + (double)sbc[0];
  double s2 = a2*wi + (double)sbc[1];
  float s = (float)(0.5*(s1+s2));
  scl[n] = s;
  unsigned u = __float_as_uint(s);
  u = (u & 0x80000000u) ? ~u : (u | 0x80000000u);  // order-preserving (ascending)
  unsigned kd = ~u;                                 // descending score
  key[n] = ((unsigned long long)kd<<32) | (unsigned)n;
  __syncthreads();
  for (int k=2; k<=NPG; k<<=1){
    for (int j=k>>1; j>0; j>>=1){
      int ixj = n ^ j;
      if (ixj > n){
        unsigned long long a = key[n], b = key[ixj];
        bool up = ((n & k) == 0);
        if ((a > b) == up){ key[n] = b; key[ixj] = a; }
      }
      __syncthreads();
    }
  }
  if (n < KEEP){
    int idx = (int)(key[n] & 0xFFFFFFFFull);
    perm[g*KEEP + n] = g*NPG + idx;
    gate[g*KEEP + n] = tanhf(scl[idx]);
  }
}

// -------- gated gather + pooled write + partial max/sum (8 blocks per graph) --------

__global__ __launch_bounds__(256) void readout_kernel(const u16* __restrict__ Hb,
    const int* __restrict__ perm, const float* __restrict__ gate,
    float* __restrict__ outp, float* __restrict__ gmx, float* __restrict__ gsm)
{
  __shared__ float4 redmx[128], redsm[128];
  int b = blockIdx.x;          // 512 blocks: graph g = b>>3, rank segment seg = b&7
  int g = b >> 3, seg = b & 7;
  int t = threadIdx.x, half = t >> 7, c = t & 127;
  float4 mx = {-INFINITY,-INFINITY,-INFINITY,-INFINITY};
  float4 sm = {0.f,0.f,0.f,0.f};
  int base = seg*32;
  for (int rI = base + half; rI < base + 32; rI += 2){
    int node = perm[g*KEEP + rI];
    float gt = gate[g*KEEP + rI];
    ushort4 hv = *(const ushort4*)(Hb + (size_t)node*D + c*4);
    float4 vv;
    vv.x = b2f(hv.x)*gt; vv.y = b2f(hv.y)*gt;
    vv.z = b2f(hv.z)*gt; vv.w = b2f(hv.w)*gt;
    ((float4*)(outp + (size_t)(g*KEEP + rI)*D))[c] = vv;
    mx.x = fmaxf(mx.x, vv.x); mx.y = fmaxf(mx.y, vv.y);
    mx.z = fmaxf(mx.z, vv.z); mx.w = fmaxf(mx.w, vv.w);
    sm.x += vv.x; sm.y += vv.y; sm.z += vv.z; sm.w += vv.w;
  }
  if (half == 1){ redmx[c] = mx; redsm[c] = sm; }
  __syncthreads();
  if (half == 0){
    float4 omx = redmx[c], osm = redsm[c];
    mx.x = fmaxf(mx.x, omx.x); mx.y = fmaxf(mx.y, omx.y);
    mx.z = fmaxf(mx.z, omx.z); mx.w = fmaxf(mx.w, omx.w);
    sm.x += osm.x; sm.y += osm.y; sm.z += osm.z; sm.w += osm.w;
    ((float4*)(gmx + (size_t)b*512))[c] = mx;
    ((float4*)(gsm + (size_t)b*512))[c] = sm;
  }
}

// -------- fold 8 segment partials into g_out --------

__global__ __launch_bounds__(512) void combine_kernel(const float* __restrict__ gmx,
    const float* __restrict__ gsm, float* __restrict__ outg)
{
  int g = blockIdx.x, d = threadIdx.x;
  float mx = -INFINITY, sm = 0.f;
  #pragma unroll
  for (int s=0; s<8; s++){
    mx = fmaxf(mx, gmx[(size_t)(g*8+s)*512 + d]);
    sm += gsm[(size_t)(g*8+s)*512 + d];
  }
  outg[(size_t)g*1024 + d] = mx;
  outg[(size_t)g*1024 + 512 + d] = sm;
}

// ---------------- launch ----------------

extern "C" void kernel_launch(void* const* d_in, const int* in_sizes, int n_in,
                              void* d_out, int out_size, void* d_ws, size_t ws_size,
                              hipStream_t stream)
{
  (void)in_sizes; (void)n_in; (void)out_size; (void)ws_size;
  const void* x   = d_in[0];
  const int* src  = (const int*)d_in[1];
  const int* dst  = (const int*)d_in[2];
  const void* W1  = d_in[3];
  const void* b1  = d_in[4];
  const void* W2  = d_in[5];
  const void* b2  = d_in[6];
  const void* sW1 = d_in[7];
  const void* sb1 = d_in[8];
  const void* sW2 = d_in[9];
  const void* sb2 = d_in[10];
  float* out = (float*)d_out;

  char* ws = (char*)d_ws;
  size_t off = 0;
  auto alloc = [&](size_t bytes){ void* p = ws + off; off += (bytes + 255) & ~(size_t)255; return p; };
  float* no     = (float*)alloc((size_t)NN*4);
  float* ni     = (float*)alloc((size_t)NN*4);
  int*   rowp   = (int*)  alloc((size_t)(NN+1)*4);
  float* t1     = (float*)alloc((size_t)NN*4);
  float* t2     = (float*)alloc((size_t)NN*4);
  int*   perm   = (int*)  alloc((size_t)NB*KEEP*4);
  float* gate   = (float*)alloc((size_t)NB*KEEP*4);
  float* b1c    = (float*)alloc((size_t)D*4);
  float* b2c    = (float*)alloc((size_t)D*4);
  float* sW1c   = (float*)alloc((size_t)D*4);
  float* sW2c   = (float*)alloc((size_t)D*4);
  float* sbc    = (float*)alloc(2*4);
  float* gmx    = (float*)alloc((size_t)512*512*4);
  float* gsm    = (float*)alloc((size_t)512*512*4);
  u16*   W1Th   = (u16*)  alloc((size_t)D*D*2);
  u16*   W1Tl   = (u16*)  alloc((size_t)D*D*2);
  u16*   W2Th   = (u16*)  alloc((size_t)D*D*2);
  u16*   W2Tl   = (u16*)  alloc((size_t)D*D*2);
  int*   csr    = (int*)  alloc((size_t)EDGES*4);
  u16*   Hh     = (u16*)  alloc((size_t)NN*D*2);
  u16*   Hl     = (u16*)  alloc((size_t)NN*D*2);
  float* Y      = (float*)alloc((size_t)NN*D*4);
  u16*   Xh     = (u16*)  alloc((size_t)NN*D*2);
  u16*   Xl     = (u16*)  alloc((size_t)NN*D*2);
  u16*   Hb     = Hh;   // bf16 h2 reuses Hh in agg mode 1

  prep_kernel<<<2048, 512, 0, stream>>>(src, dst, no, ni, rowp, csr, x,
                                        b1, b2, sW1, sW2, sb1, sb2,
                                        b1c, b2c, sW1c, sW2c, sbc,
                                        W1, W2, W1Th, W1Tl, W2Th, W2Tl, Xh, Xl);

  // conv1: Y = (x @ W1) * no ; h1 = relu(agg) -> split bf16 (Hh, Hl)
  gemm256<<<256, 512, 0, stream>>>(Xh, Xl, W1Th, W1Tl, Y, no);
  agg_kernel<<<NN/2, 256, 0, stream>>>(Y, rowp, csr, ni, b1c, Hh, Hl,
                                       nullptr, nullptr, nullptr, nullptr, 0);
  // conv2: Y = (h1 @ W2) * no ; h2 = relu(agg) -> bf16 Hb + fused score dots
  gemm256<<<256, 512, 0, stream>>>(Hh, Hl, W2Th, W2Tl, Y, no);
  agg_kernel<<<NN/2, 256, 0, stream>>>(Y, rowp, csr, ni, b2c, Hb, nullptr,
                                       sW1c, sW2c, t1, t2, 1);

  scoretopk_kernel<<<NB, 512, 0, stream>>>(t1, t2, rowp, csr, no, ni, sbc, perm, gate);
  readout_kernel  <<<512, 256, 0, stream>>>(Hb, perm, gate, out, gmx, gsm);
  combine_kernel  <<<NB, 512, 0, stream>>>(gmx, gsm, out + (size_t)NB*KEEP*D);
}